// Round 1
// baseline (437.219 us; speedup 1.0000x reference)
//
#include <hip/hip_runtime.h>
#include <math.h>

#define DIMX 512
#define NHEADS 8
#define DH 64
#define MF 266            // real feature count
#define MP 272            // padded feature count (16-multiple)
#define NB 2
#define NSEQ 2048
#define NROWS (NB*NSEQ)   // 4096
#define NBH 16
#define CHK 128
#define NCH 16
#define EPSF 1e-4f

__device__ __forceinline__ unsigned fkey(float f){
    unsigned u = __float_as_uint(f);
    return (f < 0.0f) ? ~u : (u | 0x80000000u);
}
__device__ __forceinline__ float fdec(unsigned k){
    unsigned u = (k & 0x80000000u) ? (k & 0x7fffffffu) : ~k;
    return __uint_as_float(u);
}

// C[M][N] = A[M][K] @ B[K][N] (+bias), 64x64 tile, 256 thr, 4x4 micro
__global__ __launch_bounds__(256) void gemm_f32(
    const float* __restrict__ A, const float* __restrict__ Bm,
    const float* __restrict__ bias, float* __restrict__ C,
    int M, int N, int K)
{
    __shared__ float As[16][68];
    __shared__ float Bs[16][64];
    const int tid = threadIdx.x;
    const int tx = tid & 15, ty = tid >> 4;
    const int col0 = blockIdx.x * 64, row0 = blockIdx.y * 64;
    const int lr = tid & 63, lq = tid >> 6;
    const int bkk = tid >> 4, bq = tid & 15;
    float acc[4][4] = {};
    for (int k0 = 0; k0 < K; k0 += 16) {
        float4 av = *(const float4*)&A[(size_t)(row0+lr)*K + k0 + lq*4];
        float4 bv = *(const float4*)&Bm[(size_t)(k0+bkk)*N + col0 + bq*4];
        __syncthreads();
        As[lq*4+0][lr] = av.x; As[lq*4+1][lr] = av.y;
        As[lq*4+2][lr] = av.z; As[lq*4+3][lr] = av.w;
        *(float4*)&Bs[bkk][bq*4] = bv;
        __syncthreads();
        #pragma unroll
        for (int kk = 0; kk < 16; kk++) {
            float4 a = *(const float4*)&As[kk][ty*4];
            float4 b = *(const float4*)&Bs[kk][tx*4];
            float ar[4] = {a.x,a.y,a.z,a.w};
            float br[4] = {b.x,b.y,b.z,b.w};
            #pragma unroll
            for (int i = 0; i < 4; i++)
                #pragma unroll
                for (int j = 0; j < 4; j++)
                    acc[i][j] = fmaf(ar[i], br[j], acc[i][j]);
        }
    }
    #pragma unroll
    for (int i = 0; i < 4; i++) {
        float4 o = make_float4(acc[i][0], acc[i][1], acc[i][2], acc[i][3]);
        if (bias) {
            float4 bb = *(const float4*)&bias[col0 + tx*4];
            o.x += bb.x; o.y += bb.y; o.z += bb.z; o.w += bb.w;
        }
        *(float4*)&C[(size_t)(row0 + ty*4 + i)*N + col0 + tx*4] = o;
    }
}

// Feature map dash = (nrm*data) @ proj^T for a 64-row tile of one (b,h).
// IS_Q: finalize qp = ratio*(exp(dash - diag - rowmax)+eps).
// !IS_Q: store raw dash, diag, atomicMax global max.
template<bool IS_Q>
__global__ __launch_bounds__(256) void feat_kernel(
    const float* __restrict__ qkv, const float* __restrict__ proj,
    float* __restrict__ outp, float* __restrict__ diag_out,
    unsigned* __restrict__ gmax, int coff, float nrm, float ratio)
{
    __shared__ float As[64][68];     // As[k][row]
    __shared__ float Bs[16][MP+1];   // Bs[kk][m] per k-step
    const int tid = threadIdx.x;
    const int tx = tid & 15, ty = tid >> 4;
    const int bh = blockIdx.y, b = bh >> 3, h = bh & 7;
    const int n0 = blockIdx.x * 64;
    {
        const int r = tid & 63, lq = tid >> 6;
        const float* src = &qkv[(size_t)(b*NSEQ + n0 + r)*(3*DIMX) + coff + h*DH];
        #pragma unroll
        for (int qq = 0; qq < 4; qq++) {
            int c = lq*16 + qq*4;
            float4 f = *(const float4*)&src[c];
            As[c+0][r]=f.x; As[c+1][r]=f.y; As[c+2][r]=f.z; As[c+3][r]=f.w;
        }
    }
    float dash[4][17];
    #pragma unroll
    for (int i=0;i<4;i++)
        #pragma unroll
        for (int j=0;j<17;j++) dash[i][j] = 0.f;
    float dsq[4] = {0.f,0.f,0.f,0.f};
    for (int s = 0; s < 4; s++) {
        __syncthreads();
        for (int idx = tid; idx < MP*4; idx += 256) {
            int m = idx >> 2, qq = idx & 3;
            float4 f = make_float4(0.f,0.f,0.f,0.f);
            if (m < MF) f = *(const float4*)&proj[m*DH + s*16 + qq*4];
            Bs[qq*4+0][m]=f.x; Bs[qq*4+1][m]=f.y; Bs[qq*4+2][m]=f.z; Bs[qq*4+3][m]=f.w;
        }
        __syncthreads();
        #pragma unroll
        for (int kk = 0; kk < 16; kk++) {
            float4 a = *(const float4*)&As[s*16+kk][ty*4];
            float ar[4] = {a.x,a.y,a.z,a.w};
            #pragma unroll
            for (int i=0;i<4;i++) dsq[i] = fmaf(ar[i], ar[i], dsq[i]);
            #pragma unroll
            for (int jj = 0; jj < 17; jj++) {
                float bv = Bs[kk][tx + 16*jj];
                #pragma unroll
                for (int i=0;i<4;i++) dash[i][jj] = fmaf(ar[i], bv, dash[i][jj]);
            }
        }
    }
    const size_t rbase = (size_t)bh*NSEQ + n0 + ty*4;
    if (IS_Q) {
        #pragma unroll
        for (int i=0;i<4;i++){
            float diag = 0.0625f * dsq[i];
            float mx = -1e30f;
            #pragma unroll
            for (int jj=0;jj<17;jj++){
                dash[i][jj] *= nrm;
                if (tx + 16*jj < MF) mx = fmaxf(mx, dash[i][jj]);
            }
            #pragma unroll
            for (int o=1;o<16;o<<=1) mx = fmaxf(mx, __shfl_xor(mx, o, 64));
            float* orow = &outp[(rbase + i)*MP];
            #pragma unroll
            for (int jj=0;jj<17;jj++){
                int m = tx + 16*jj;
                float v = (m < MF) ? ratio*(expf(dash[i][jj] - diag - mx) + EPSF) : 0.f;
                orow[m] = v;
            }
        }
    } else {
        float wmax = -1e30f;
        #pragma unroll
        for (int i=0;i<4;i++){
            float diag = 0.0625f * dsq[i];
            if (tx == 0) diag_out[rbase + i] = diag;
            float* orow = &outp[(rbase + i)*MP];
            #pragma unroll
            for (int jj=0;jj<17;jj++){
                float d = dash[i][jj] * nrm;
                int m = tx + 16*jj;
                orow[m] = d;
                if (m < MF) wmax = fmaxf(wmax, d);
            }
        }
        #pragma unroll
        for (int o=1;o<64;o<<=1) wmax = fmaxf(wmax, __shfl_xor(wmax, o, 64));
        if ((tid & 63) == 0) atomicMax(gmax, fkey(wmax));
    }
}

__global__ __launch_bounds__(256) void kexp_kernel(
    float* __restrict__ kp, const float* __restrict__ diagk,
    const unsigned* __restrict__ gmax, float ratio)
{
    unsigned idx = blockIdx.x * 256u + threadIdx.x;
    if (idx >= (unsigned)NBH*NSEQ*MP) return;
    const float stab = fdec(*gmax);
    int m = idx % MP;
    unsigned row = idx / MP;
    float v = 0.f;
    if (m < MF) v = ratio * (expf(kp[idx] - diagk[row] - stab) + EPSF);
    kp[idx] = v;
}

// Per (b,h,chunk): KV[m][d] = K_c^T V_c, Ksum[m] = col-sums of K_c
__global__ __launch_bounds__(320) void chunk_sums_kernel(
    const float* __restrict__ kp, const float* __restrict__ qkv,
    float* __restrict__ ckv, float* __restrict__ cksum)
{
    __shared__ float vs[CHK][DH];
    const int tid = threadIdx.x;
    const int c = blockIdx.x, bh = blockIdx.y, b = bh >> 3, h = bh & 7;
    for (int idx = tid; idx < CHK*16; idx += 320) {
        int i = idx >> 4, q = idx & 15;
        *(float4*)&vs[i][q*4] =
            *(const float4*)&qkv[(size_t)(b*NSEQ + c*CHK + i)*(3*DIMX) + 2*DIMX + h*DH + q*4];
    }
    __syncthreads();
    if (tid >= 272) return;
    const int mg = tid % 68, dg = tid / 68;   // m block of 4, d block of 16
    float acc[4][16] = {};
    float ks[4] = {0.f,0.f,0.f,0.f};
    const size_t kbase = (size_t)(bh*NSEQ + c*CHK)*MP + mg*4;
    for (int i = 0; i < CHK; i++) {
        float4 kv = *(const float4*)&kp[kbase + (size_t)i*MP];
        float kr[4] = {kv.x,kv.y,kv.z,kv.w};
        if (dg == 0) { ks[0]+=kr[0]; ks[1]+=kr[1]; ks[2]+=kr[2]; ks[3]+=kr[3]; }
        #pragma unroll
        for (int t = 0; t < 4; t++) {
            float4 vv = *(const float4*)&vs[i][dg*16 + t*4];
            float vr[4] = {vv.x,vv.y,vv.z,vv.w};
            #pragma unroll
            for (int mi=0;mi<4;mi++){
                acc[mi][t*4+0] = fmaf(kr[mi], vr[0], acc[mi][t*4+0]);
                acc[mi][t*4+1] = fmaf(kr[mi], vr[1], acc[mi][t*4+1]);
                acc[mi][t*4+2] = fmaf(kr[mi], vr[2], acc[mi][t*4+2]);
                acc[mi][t*4+3] = fmaf(kr[mi], vr[3], acc[mi][t*4+3]);
            }
        }
    }
    const size_t obase = ((size_t)(bh*NCH + c)*MP + mg*4)*DH + dg*16;
    #pragma unroll
    for (int mi=0;mi<4;mi++)
        #pragma unroll
        for (int t=0;t<4;t++)
            *(float4*)&ckv[obase + (size_t)mi*DH + t*4] =
                make_float4(acc[mi][t*4], acc[mi][t*4+1], acc[mi][t*4+2], acc[mi][t*4+3]);
    if (dg == 0) {
        #pragma unroll
        for (int mi=0;mi<4;mi++)
            cksum[(size_t)(bh*NCH + c)*MP + mg*4 + mi] = ks[mi];
    }
}

__global__ __launch_bounds__(256) void prefix_kv_kernel(float* __restrict__ ckv)
{
    const int bh = blockIdx.y;
    const int md = blockIdx.x * 256 + threadIdx.x;  // < MP*DH = 17408
    float run = 0.f;
    #pragma unroll
    for (int c = 0; c < NCH; c++) {
        size_t idx = (size_t)(bh*NCH + c)*MP*DH + md;
        float v = ckv[idx];
        ckv[idx] = run;
        run += v;
    }
}

__global__ __launch_bounds__(320) void prefix_ksum_kernel(float* __restrict__ cksum)
{
    const int bh = blockIdx.x;
    const int m = threadIdx.x;
    if (m >= MP) return;
    float run = 0.f;
    #pragma unroll
    for (int c = 0; c < NCH; c++) {
        size_t idx = (size_t)(bh*NCH + c)*MP + m;
        float v = cksum[idx];
        cksum[idx] = run;
        run += v;
    }
}

// q'_nm = qp_nm / (exclusive-chunk-prefix + within-chunk inclusive cumsum of kp)
__global__ __launch_bounds__(320) void qprime_kernel(
    float* __restrict__ qp, const float* __restrict__ kp, const float* __restrict__ cksum)
{
    const int c = blockIdx.x, bh = blockIdx.y;
    const int m = threadIdx.x;
    if (m >= MP) return;
    float run = cksum[(size_t)(bh*NCH + c)*MP + m];
    size_t base = (size_t)(bh*NSEQ + c*CHK)*MP + m;
    for (int i = 0; i < CHK; i++) {
        size_t idx = base + (size_t)i*MP;
        run += kp[idx];
        float q = qp[idx];
        qp[idx] = (m < MF) ? q / run : 0.f;
    }
}

// Per (b,h,chunk): out = Q'@S + tril(Q'K^T)@V   -> aout [NROWS][DIMX]
__global__ __launch_bounds__(256) void attn_kernel(
    const float* __restrict__ qp, const float* __restrict__ kp,
    const float* __restrict__ qkv, const float* __restrict__ ckv,
    float* __restrict__ aout)
{
    __shared__ float P[CHK][132];
    __shared__ float Qs[16][132];
    __shared__ float Ks[16][132];
    const int tid = threadIdx.x, tx = tid & 15, ty = tid >> 4;
    const int c = blockIdx.x, bh = blockIdx.y, b = bh >> 3, h = bh & 7;
    const size_t rowg = (size_t)bh*NSEQ + c*CHK;   // qp/kp row base
    const size_t rowx = (size_t)b*NSEQ + c*CHK;    // qkv/aout row base
    // ---- phase 1: P = tril(Q' K^T), 8x8 micro
    float acc[8][8] = {};
    for (int m0 = 0; m0 < MP; m0 += 16) {
        __syncthreads();
        for (int idx = tid; idx < 512; idx += 256) {
            int i = idx >> 2, q = idx & 3;
            float4 f = *(const float4*)&qp[(rowg+i)*MP + m0 + q*4];
            Qs[q*4+0][i]=f.x; Qs[q*4+1][i]=f.y; Qs[q*4+2][i]=f.z; Qs[q*4+3][i]=f.w;
            float4 g = *(const float4*)&kp[(rowg+i)*MP + m0 + q*4];
            Ks[q*4+0][i]=g.x; Ks[q*4+1][i]=g.y; Ks[q*4+2][i]=g.z; Ks[q*4+3][i]=g.w;
        }
        __syncthreads();
        #pragma unroll
        for (int mm = 0; mm < 16; mm++) {
            float4 a0 = *(const float4*)&Qs[mm][ty*8];
            float4 a1 = *(const float4*)&Qs[mm][ty*8+4];
            float4 b0 = *(const float4*)&Ks[mm][tx*8];
            float4 b1 = *(const float4*)&Ks[mm][tx*8+4];
            float ar[8] = {a0.x,a0.y,a0.z,a0.w,a1.x,a1.y,a1.z,a1.w};
            float br[8] = {b0.x,b0.y,b0.z,b0.w,b1.x,b1.y,b1.z,b1.w};
            #pragma unroll
            for (int i=0;i<8;i++)
                #pragma unroll
                for (int j=0;j<8;j++)
                    acc[i][j] = fmaf(ar[i], br[j], acc[i][j]);
        }
    }
    __syncthreads();
    #pragma unroll
    for (int i=0;i<8;i++){
        int r = ty*8+i;
        #pragma unroll
        for (int j=0;j<8;j++){
            int cc = tx*8+j;
            P[r][cc] = (cc <= r) ? acc[i][j] : 0.f;
        }
    }
    // ---- phase 2: out[128][64] = Q'@S + P@V, 8x4 micro
    float o[8][4] = {};
    for (int m0 = 0; m0 < MP; m0 += 16) {
        __syncthreads();
        for (int idx = tid; idx < 512; idx += 256) {
            int i = idx >> 2, q = idx & 3;
            float4 f = *(const float4*)&qp[(rowg+i)*MP + m0 + q*4];
            Qs[q*4+0][i]=f.x; Qs[q*4+1][i]=f.y; Qs[q*4+2][i]=f.z; Qs[q*4+3][i]=f.w;
        }
        {
            int mm = tid >> 4, q = tid & 15;
            *(float4*)&Ks[mm][q*4] =
                *(const float4*)&ckv[((size_t)(bh*NCH + c)*MP + m0 + mm)*DH + q*4];
        }
        __syncthreads();
        #pragma unroll
        for (int mm=0;mm<16;mm++){
            float4 a0 = *(const float4*)&Qs[mm][ty*8];
            float4 a1 = *(const float4*)&Qs[mm][ty*8+4];
            float4 bv = *(const float4*)&Ks[mm][tx*4];
            float ar[8] = {a0.x,a0.y,a0.z,a0.w,a1.x,a1.y,a1.z,a1.w};
            float br[4] = {bv.x,bv.y,bv.z,bv.w};
            #pragma unroll
            for (int i=0;i<8;i++)
                #pragma unroll
                for (int j=0;j<4;j++)
                    o[i][j] = fmaf(ar[i], br[j], o[i][j]);
        }
    }
    for (int j0 = 0; j0 < CHK; j0 += 16) {
        __syncthreads();
        {
            int jj = tid >> 4, q = tid & 15;
            *(float4*)&Ks[jj][q*4] =
                *(const float4*)&qkv[(rowx + j0 + jj)*(3*DIMX) + 2*DIMX + h*DH + q*4];
        }
        __syncthreads();
        #pragma unroll
        for (int jj=0;jj<16;jj++){
            float4 bv = *(const float4*)&Ks[jj][tx*4];
            float br[4] = {bv.x,bv.y,bv.z,bv.w};
            #pragma unroll
            for (int i=0;i<8;i++){
                float a = P[ty*8+i][j0+jj];
                o[i][0] = fmaf(a, br[0], o[i][0]);
                o[i][1] = fmaf(a, br[1], o[i][1]);
                o[i][2] = fmaf(a, br[2], o[i][2]);
                o[i][3] = fmaf(a, br[3], o[i][3]);
            }
        }
    }
    #pragma unroll
    for (int i=0;i<8;i++){
        *(float4*)&aout[(rowx + ty*8 + i)*DIMX + h*DH + tx*4] =
            make_float4(o[i][0], o[i][1], o[i][2], o[i][3]);
    }
}

extern "C" void kernel_launch(void* const* d_in, const int* in_sizes, int n_in,
                              void* d_out, int out_size, void* d_ws, size_t ws_size,
                              hipStream_t stream)
{
    (void)in_sizes; (void)n_in; (void)out_size; (void)ws_size;
    const float* x     = (const float*)d_in[0];
    const float* w_qkv = (const float*)d_in[1];
    const float* w_out = (const float*)d_in[2];
    const float* b_out = (const float*)d_in[3];
    const float* proj  = (const float*)d_in[4];
    float* out = (float*)d_out;

    char* ws = (char*)d_ws;
    size_t off = 0;
    auto alloc = [&](size_t bytes) -> char* {
        char* p = ws + off;
        off += (bytes + 255) & ~(size_t)255;
        return p;
    };
    float* qkv     = (float*)alloc((size_t)NROWS*3*DIMX*sizeof(float));     // 25.2 MB
    float* qp      = (float*)alloc((size_t)NBH*NSEQ*MP*sizeof(float));      // 35.7 MB
    float* kp      = (float*)alloc((size_t)NBH*NSEQ*MP*sizeof(float));      // 35.7 MB
    float* diagk   = (float*)alloc((size_t)NBH*NSEQ*sizeof(float));
    unsigned* gmax = (unsigned*)alloc(256);
    float* ckv     = (float*)alloc((size_t)NBH*NCH*MP*DH*sizeof(float));    // 17.8 MB
    float* cksum   = (float*)alloc((size_t)NBH*NCH*MP*sizeof(float));
    float* aout    = (float*)alloc((size_t)NROWS*DIMX*sizeof(float));       // 8.4 MB

    const float nrm   = (float)pow(64.0, -0.25);   // 2^-1.5
    const float ratio = (float)(1.0 / sqrt(266.0));

    hipMemsetAsync(gmax, 0, sizeof(unsigned), stream);
    // qkv = x @ w_qkv
    gemm_f32<<<dim3(24, 64), 256, 0, stream>>>(x, w_qkv, nullptr, qkv, NROWS, 3*DIMX, DIMX);
    // feature maps
    feat_kernel<true ><<<dim3(32, 16), 256, 0, stream>>>(qkv, proj, qp, nullptr, nullptr, 0, nrm, ratio);
    feat_kernel<false><<<dim3(32, 16), 256, 0, stream>>>(qkv, proj, kp, diagk, gmax, DIMX, nrm, ratio);
    kexp_kernel<<<dim3((NBH*NSEQ*MP)/256), 256, 0, stream>>>(kp, diagk, gmax, ratio);
    // chunk scan
    chunk_sums_kernel<<<dim3(NCH, NBH), 320, 0, stream>>>(kp, qkv, ckv, cksum);
    prefix_kv_kernel<<<dim3(68, NBH), 256, 0, stream>>>(ckv);
    prefix_ksum_kernel<<<dim3(NBH), 320, 0, stream>>>(cksum);
    qprime_kernel<<<dim3(NCH, NBH), 320, 0, stream>>>(qp, kp, cksum);
    attn_kernel<<<dim3(NCH, NBH), 256, 0, stream>>>(qp, kp, qkv, ckv, aout);
    // out = aout @ w_out + b_out
    gemm_f32<<<dim3(8, 64), 256, 0, stream>>>(aout, w_out, b_out, out, NROWS, DIMX, DIMX);
}

// Round 3
// 347.419 us; speedup vs baseline: 1.2585x; 1.2585x over previous
//
#include <hip/hip_runtime.h>
#include <math.h>

#define DIMX 512
#define NHEADS 8
#define DH 64
#define MF 266            // real feature count
#define MP 272            // padded feature count (16-multiple)
#define NB 2
#define NSEQ 2048
#define NROWS (NB*NSEQ)   // 4096
#define NBH 16
#define CHK 64
#define NCH 32
#define EPSF 1e-4f

__device__ __forceinline__ unsigned fkey(float f){
    unsigned u = __float_as_uint(f);
    return (f < 0.0f) ? ~u : (u | 0x80000000u);
}
__device__ __forceinline__ float fdec(unsigned k){
    unsigned u = (k & 0x80000000u) ? (k & 0x7fffffffu) : ~k;
    return __uint_as_float(u);
}

// C[M][N] = A[M][K] @ B[K][N] (+bias), 64x64 tile, 256 thr, 4x4 micro
__global__ __launch_bounds__(256) void gemm_f32(
    const float* __restrict__ A, const float* __restrict__ Bm,
    const float* __restrict__ bias, float* __restrict__ C,
    int M, int N, int K)
{
    __shared__ float As[16][68];
    __shared__ float Bs[16][64];
    const int tid = threadIdx.x;
    const int tx = tid & 15, ty = tid >> 4;
    const int col0 = blockIdx.x * 64, row0 = blockIdx.y * 64;
    const int lr = tid & 63, lq = tid >> 6;
    const int bkk = tid >> 4, bq = tid & 15;
    float acc[4][4] = {};
    for (int k0 = 0; k0 < K; k0 += 16) {
        float4 av = *(const float4*)&A[(size_t)(row0+lr)*K + k0 + lq*4];
        float4 bv = *(const float4*)&Bm[(size_t)(k0+bkk)*N + col0 + bq*4];
        __syncthreads();
        As[lq*4+0][lr] = av.x; As[lq*4+1][lr] = av.y;
        As[lq*4+2][lr] = av.z; As[lq*4+3][lr] = av.w;
        *(float4*)&Bs[bkk][bq*4] = bv;
        __syncthreads();
        #pragma unroll
        for (int kk = 0; kk < 16; kk++) {
            float4 a = *(const float4*)&As[kk][ty*4];
            float4 b = *(const float4*)&Bs[kk][tx*4];
            float ar[4] = {a.x,a.y,a.z,a.w};
            float br[4] = {b.x,b.y,b.z,b.w};
            #pragma unroll
            for (int i = 0; i < 4; i++)
                #pragma unroll
                for (int j = 0; j < 4; j++)
                    acc[i][j] = fmaf(ar[i], br[j], acc[i][j]);
        }
    }
    #pragma unroll
    for (int i = 0; i < 4; i++) {
        float4 o = make_float4(acc[i][0], acc[i][1], acc[i][2], acc[i][3]);
        if (bias) {
            float4 bb = *(const float4*)&bias[col0 + tx*4];
            o.x += bb.x; o.y += bb.y; o.z += bb.z; o.w += bb.w;
        }
        *(float4*)&C[(size_t)(row0 + ty*4 + i)*N + col0 + tx*4] = o;
    }
}

// Feature map dash = (nrm*data) @ proj^T for a 64-row tile of one (b,h).
template<bool IS_Q>
__global__ __launch_bounds__(256) void feat_kernel(
    const float* __restrict__ qkv, const float* __restrict__ proj,
    float* __restrict__ outp, float* __restrict__ diag_out,
    unsigned* __restrict__ gmax, int coff, float nrm, float ratio)
{
    __shared__ float As[64][68];     // As[k][row]
    __shared__ float Bs[16][MP+1];   // Bs[kk][m] per k-step
    const int tid = threadIdx.x;
    const int tx = tid & 15, ty = tid >> 4;
    const int bh = blockIdx.y, b = bh >> 3, h = bh & 7;
    const int n0 = blockIdx.x * 64;
    {
        const int r = tid & 63, lq = tid >> 6;
        const float* src = &qkv[(size_t)(b*NSEQ + n0 + r)*(3*DIMX) + coff + h*DH];
        #pragma unroll
        for (int qq = 0; qq < 4; qq++) {
            int c = lq*16 + qq*4;
            float4 f = *(const float4*)&src[c];
            As[c+0][r]=f.x; As[c+1][r]=f.y; As[c+2][r]=f.z; As[c+3][r]=f.w;
        }
    }
    float dash[4][17];
    #pragma unroll
    for (int i=0;i<4;i++)
        #pragma unroll
        for (int j=0;j<17;j++) dash[i][j] = 0.f;
    float dsq[4] = {0.f,0.f,0.f,0.f};
    for (int s = 0; s < 4; s++) {
        __syncthreads();
        for (int idx = tid; idx < MP*4; idx += 256) {
            int m = idx >> 2, qq = idx & 3;
            float4 f = make_float4(0.f,0.f,0.f,0.f);
            if (m < MF) f = *(const float4*)&proj[m*DH + s*16 + qq*4];
            Bs[qq*4+0][m]=f.x; Bs[qq*4+1][m]=f.y; Bs[qq*4+2][m]=f.z; Bs[qq*4+3][m]=f.w;
        }
        __syncthreads();
        #pragma unroll
        for (int kk = 0; kk < 16; kk++) {
            float4 a = *(const float4*)&As[s*16+kk][ty*4];
            float ar[4] = {a.x,a.y,a.z,a.w};
            #pragma unroll
            for (int i=0;i<4;i++) dsq[i] = fmaf(ar[i], ar[i], dsq[i]);
            #pragma unroll
            for (int jj = 0; jj < 17; jj++) {
                float bv = Bs[kk][tx + 16*jj];
                #pragma unroll
                for (int i=0;i<4;i++) dash[i][jj] = fmaf(ar[i], bv, dash[i][jj]);
            }
        }
    }
    const size_t rbase = (size_t)bh*NSEQ + n0 + ty*4;
    if (IS_Q) {
        #pragma unroll
        for (int i=0;i<4;i++){
            float diag = 0.0625f * dsq[i];
            float mx = -1e30f;
            #pragma unroll
            for (int jj=0;jj<17;jj++){
                dash[i][jj] *= nrm;
                if (tx + 16*jj < MF) mx = fmaxf(mx, dash[i][jj]);
            }
            #pragma unroll
            for (int o=1;o<16;o<<=1) mx = fmaxf(mx, __shfl_xor(mx, o, 64));
            float* orow = &outp[(rbase + i)*MP];
            #pragma unroll
            for (int jj=0;jj<17;jj++){
                int m = tx + 16*jj;
                float v = (m < MF) ? ratio*(expf(dash[i][jj] - diag - mx) + EPSF) : 0.f;
                orow[m] = v;
            }
        }
    } else {
        float wmax = -1e30f;
        #pragma unroll
        for (int i=0;i<4;i++){
            float diag = 0.0625f * dsq[i];
            if (tx == 0) diag_out[rbase + i] = diag;
            float* orow = &outp[(rbase + i)*MP];
            #pragma unroll
            for (int jj=0;jj<17;jj++){
                float d = dash[i][jj] * nrm;
                int m = tx + 16*jj;
                orow[m] = d;
                if (m < MF) wmax = fmaxf(wmax, d);
            }
        }
        #pragma unroll
        for (int o=1;o<64;o<<=1) wmax = fmaxf(wmax, __shfl_xor(wmax, o, 64));
        if ((tid & 63) == 0) atomicMax(gmax, fkey(wmax));
    }
}

__global__ __launch_bounds__(256) void kexp_kernel(
    float* __restrict__ kp, const float* __restrict__ diagk,
    const unsigned* __restrict__ gmax, float ratio)
{
    unsigned idx4 = (blockIdx.x * 256u + threadIdx.x) * 4u;
    if (idx4 >= (unsigned)NBH*NSEQ*MP) return;
    const float stab = fdec(*gmax);
    int m = idx4 % MP;
    unsigned row = idx4 / MP;
    float dg = diagk[row];
    float4 v = *(float4*)&kp[idx4];
    float r[4] = {v.x,v.y,v.z,v.w};
    #pragma unroll
    for (int j = 0; j < 4; j++)
        r[j] = (m + j < MF) ? ratio * (expf(r[j] - dg - stab) + EPSF) : 0.f;
    *(float4*)&kp[idx4] = make_float4(r[0],r[1],r[2],r[3]);
}

// Per (b,h,chunk): KV[m][d] = K_c^T V_c, Ksum[m] = col-sums of K_c
__global__ __launch_bounds__(320) void chunk_sums_kernel(
    const float* __restrict__ kp, const float* __restrict__ qkv,
    float* __restrict__ ckv, float* __restrict__ cksum)
{
    __shared__ float vs[CHK][DH];
    const int tid = threadIdx.x;
    const int c = blockIdx.x, bh = blockIdx.y, b = bh >> 3, h = bh & 7;
    for (int idx = tid; idx < CHK*16; idx += 320) {
        int i = idx >> 4, q = idx & 15;
        *(float4*)&vs[i][q*4] =
            *(const float4*)&qkv[(size_t)(b*NSEQ + c*CHK + i)*(3*DIMX) + 2*DIMX + h*DH + q*4];
    }
    __syncthreads();
    if (tid >= 272) return;
    const int mg = tid % 68, dg = tid / 68;   // m block of 4, d block of 16
    float acc[4][16] = {};
    float ks[4] = {0.f,0.f,0.f,0.f};
    const size_t kbase = (size_t)(bh*NSEQ + c*CHK)*MP + mg*4;
    for (int i = 0; i < CHK; i++) {
        float4 kv = *(const float4*)&kp[kbase + (size_t)i*MP];
        float kr[4] = {kv.x,kv.y,kv.z,kv.w};
        if (dg == 0) { ks[0]+=kr[0]; ks[1]+=kr[1]; ks[2]+=kr[2]; ks[3]+=kr[3]; }
        #pragma unroll
        for (int t = 0; t < 4; t++) {
            float4 vv = *(const float4*)&vs[i][dg*16 + t*4];
            float vr[4] = {vv.x,vv.y,vv.z,vv.w};
            #pragma unroll
            for (int mi=0;mi<4;mi++){
                acc[mi][t*4+0] = fmaf(kr[mi], vr[0], acc[mi][t*4+0]);
                acc[mi][t*4+1] = fmaf(kr[mi], vr[1], acc[mi][t*4+1]);
                acc[mi][t*4+2] = fmaf(kr[mi], vr[2], acc[mi][t*4+2]);
                acc[mi][t*4+3] = fmaf(kr[mi], vr[3], acc[mi][t*4+3]);
            }
        }
    }
    const size_t obase = ((size_t)(bh*NCH + c)*MP + mg*4)*DH + dg*16;
    #pragma unroll
    for (int mi=0;mi<4;mi++)
        #pragma unroll
        for (int t=0;t<4;t++)
            *(float4*)&ckv[obase + (size_t)mi*DH + t*4] =
                make_float4(acc[mi][t*4], acc[mi][t*4+1], acc[mi][t*4+2], acc[mi][t*4+3]);
    if (dg == 0) {
        #pragma unroll
        for (int mi=0;mi<4;mi++)
            cksum[(size_t)(bh*NCH + c)*MP + mg*4 + mi] = ks[mi];
    }
}

__global__ __launch_bounds__(256) void prefix_kv_kernel(float* __restrict__ ckv)
{
    const int bh = blockIdx.y;
    const int md = blockIdx.x * 256 + threadIdx.x;  // < MP*DH = 17408
    float run = 0.f;
    #pragma unroll
    for (int c = 0; c < NCH; c++) {
        size_t idx = (size_t)(bh*NCH + c)*MP*DH + md;
        float v = ckv[idx];
        ckv[idx] = run;
        run += v;
    }
}

__global__ __launch_bounds__(320) void prefix_ksum_kernel(float* __restrict__ cksum)
{
    const int bh = blockIdx.x;
    const int m = threadIdx.x;
    if (m >= MP) return;
    float run = 0.f;
    #pragma unroll
    for (int c = 0; c < NCH; c++) {
        size_t idx = (size_t)(bh*NCH + c)*MP + m;
        float v = cksum[idx];
        cksum[idx] = run;
        run += v;
    }
}

// q'_nm = qp_nm / (exclusive-chunk-prefix + within-chunk inclusive cumsum of kp)
__global__ __launch_bounds__(320) void qprime_kernel(
    float* __restrict__ qp, const float* __restrict__ kp, const float* __restrict__ cksum)
{
    const int c = blockIdx.x, bh = blockIdx.y;
    const int m = threadIdx.x;
    if (m >= MP) return;
    float run = cksum[(size_t)(bh*NCH + c)*MP + m];
    size_t base = (size_t)(bh*NSEQ + c*CHK)*MP + m;
    for (int i = 0; i < CHK; i++) {
        size_t idx = base + (size_t)i*MP;
        run += kp[idx];
        float q = qp[idx];
        qp[idx] = (m < MF) ? q / run : 0.f;
    }
}

// Per (b,h,chunk of 64): out = Q'@S + tril(Q'K^T)@V
// 256 thr as 16x16, 4x4 micro over 64x64 tiles. Fused single m-pass for
// P-accum and Q'@S, then PV from LDS.
__global__ __launch_bounds__(256) void attn_kernel(
    const float* __restrict__ qp, const float* __restrict__ kp,
    const float* __restrict__ qkv, const float* __restrict__ ckv,
    float* __restrict__ aout)
{
    __shared__ float Qs[16][68];
    __shared__ float Ks[16][68];
    __shared__ float Ss[16][68];
    __shared__ float Vs[CHK][68];
    __shared__ float P[CHK][76];   // stride 76: row-step = 16 banks (2-way, free)
    const int tid = threadIdx.x, tx = tid & 15, ty = tid >> 4;
    const int c = blockIdx.x, bh = blockIdx.y, b = bh >> 3, h = bh & 7;
    const size_t rowg = (size_t)bh*NSEQ + c*CHK;   // qp/kp row base
    const size_t rowx = (size_t)b*NSEQ + c*CHK;    // qkv/aout row base

    // load V chunk once
    for (int idx = tid; idx < CHK*16; idx += 256) {
        int i = idx >> 4, q = idx & 15;
        *(float4*)&Vs[i][q*4] =
            *(const float4*)&qkv[(rowx + i)*(3*DIMX) + 2*DIMX + h*DH + q*4];
    }

    float accP[4][4] = {};
    float accO[4][4] = {};
    // one pass over m: accumulate P = Q'K^T and O = Q'@S
    const int ldi = tid >> 2, ldq = tid & 3;   // 64 rows x 4 quads
    const int smm = tid >> 4, smq = tid & 15;  // 16 rows x 16 quads
    for (int m0 = 0; m0 < MP; m0 += 16) {
        __syncthreads();
        {
            float4 f = *(const float4*)&qp[(rowg + ldi)*MP + m0 + ldq*4];
            Qs[ldq*4+0][ldi]=f.x; Qs[ldq*4+1][ldi]=f.y; Qs[ldq*4+2][ldi]=f.z; Qs[ldq*4+3][ldi]=f.w;
            float4 g = *(const float4*)&kp[(rowg + ldi)*MP + m0 + ldq*4];
            Ks[ldq*4+0][ldi]=g.x; Ks[ldq*4+1][ldi]=g.y; Ks[ldq*4+2][ldi]=g.z; Ks[ldq*4+3][ldi]=g.w;
            *(float4*)&Ss[smm][smq*4] =
                *(const float4*)&ckv[((size_t)(bh*NCH + c)*MP + m0 + smm)*DH + smq*4];
        }
        __syncthreads();
        #pragma unroll
        for (int kk = 0; kk < 16; kk++) {
            float4 a = *(const float4*)&Qs[kk][ty*4];
            float4 bk = *(const float4*)&Ks[kk][tx*4];
            float4 bs = *(const float4*)&Ss[kk][tx*4];
            float ar[4] = {a.x,a.y,a.z,a.w};
            float kr[4] = {bk.x,bk.y,bk.z,bk.w};
            float sr[4] = {bs.x,bs.y,bs.z,bs.w};
            #pragma unroll
            for (int i=0;i<4;i++)
                #pragma unroll
                for (int j=0;j<4;j++) {
                    accP[i][j] = fmaf(ar[i], kr[j], accP[i][j]);
                    accO[i][j] = fmaf(ar[i], sr[j], accO[i][j]);
                }
        }
    }
    // write masked P
    #pragma unroll
    for (int i=0;i<4;i++){
        int r = ty*4+i;
        float4 o;
        o.x = (tx*4+0 <= r) ? accP[i][0] : 0.f;
        o.y = (tx*4+1 <= r) ? accP[i][1] : 0.f;
        o.z = (tx*4+2 <= r) ? accP[i][2] : 0.f;
        o.w = (tx*4+3 <= r) ? accP[i][3] : 0.f;
        *(float4*)&P[r][tx*4] = o;
    }
    __syncthreads();
    // O += P @ V
    #pragma unroll 4
    for (int kk = 0; kk < CHK; kk++) {
        float4 vv = *(const float4*)&Vs[kk][tx*4];
        float vr[4] = {vv.x,vv.y,vv.z,vv.w};
        #pragma unroll
        for (int i=0;i<4;i++){
            float a = P[ty*4+i][kk];
            accO[i][0] = fmaf(a, vr[0], accO[i][0]);
            accO[i][1] = fmaf(a, vr[1], accO[i][1]);
            accO[i][2] = fmaf(a, vr[2], accO[i][2]);
            accO[i][3] = fmaf(a, vr[3], accO[i][3]);
        }
    }
    #pragma unroll
    for (int i=0;i<4;i++){
        *(float4*)&aout[(rowx + ty*4 + i)*DIMX + h*DH + tx*4] =
            make_float4(accO[i][0], accO[i][1], accO[i][2], accO[i][3]);
    }
}

extern "C" void kernel_launch(void* const* d_in, const int* in_sizes, int n_in,
                              void* d_out, int out_size, void* d_ws, size_t ws_size,
                              hipStream_t stream)
{
    (void)in_sizes; (void)n_in; (void)out_size; (void)ws_size;
    const float* x     = (const float*)d_in[0];
    const float* w_qkv = (const float*)d_in[1];
    const float* w_out = (const float*)d_in[2];
    const float* b_out = (const float*)d_in[3];
    const float* proj  = (const float*)d_in[4];
    float* out = (float*)d_out;

    char* ws = (char*)d_ws;
    size_t off = 0;
    auto alloc = [&](size_t bytes) -> char* {
        char* p = ws + off;
        off += (bytes + 255) & ~(size_t)255;
        return p;
    };
    float* qkv     = (float*)alloc((size_t)NROWS*3*DIMX*sizeof(float));     // 25.2 MB
    float* qp      = (float*)alloc((size_t)NBH*NSEQ*MP*sizeof(float));      // 35.7 MB
    float* kp      = (float*)alloc((size_t)NBH*NSEQ*MP*sizeof(float));      // 35.7 MB
    float* diagk   = (float*)alloc((size_t)NBH*NSEQ*sizeof(float));
    unsigned* gmax = (unsigned*)alloc(256);
    float* ckv     = (float*)alloc((size_t)NBH*NCH*MP*DH*sizeof(float));    // 35.7 MB
    float* cksum   = (float*)alloc((size_t)NBH*NCH*MP*sizeof(float));
    float* aout    = (float*)alloc((size_t)NROWS*DIMX*sizeof(float));       // 8.4 MB

    const float nrm   = (float)pow(64.0, -0.25);   // 2^-1.5
    const float ratio = (float)(1.0 / sqrt(266.0));

    hipMemsetAsync(gmax, 0, sizeof(unsigned), stream);
    // qkv = x @ w_qkv
    gemm_f32<<<dim3(24, 64), 256, 0, stream>>>(x, w_qkv, nullptr, qkv, NROWS, 3*DIMX, DIMX);
    // feature maps
    feat_kernel<true ><<<dim3(32, 16), 256, 0, stream>>>(qkv, proj, qp, nullptr, nullptr, 0, nrm, ratio);
    feat_kernel<false><<<dim3(32, 16), 256, 0, stream>>>(qkv, proj, kp, diagk, gmax, DIMX, nrm, ratio);
    kexp_kernel<<<dim3((NBH*NSEQ*MP)/1024), 256, 0, stream>>>(kp, diagk, gmax, ratio);
    // chunk scan (C=64)
    chunk_sums_kernel<<<dim3(NCH, NBH), 320, 0, stream>>>(kp, qkv, ckv, cksum);
    prefix_kv_kernel<<<dim3(68, NBH), 256, 0, stream>>>(ckv);
    prefix_ksum_kernel<<<dim3(NBH), 320, 0, stream>>>(cksum);
    qprime_kernel<<<dim3(NCH, NBH), 320, 0, stream>>>(qp, kp, cksum);
    attn_kernel<<<dim3(NCH, NBH), 256, 0, stream>>>(qp, kp, qkv, ckv, aout);
    // out = aout @ w_out + b_out
    gemm_f32<<<dim3(8, 64), 256, 0, stream>>>(aout, w_out, b_out, out, NROWS, DIMX, DIMX);
}

// Round 6
// 295.006 us; speedup vs baseline: 1.4821x; 1.1777x over previous
//
#include <hip/hip_runtime.h>
#include <math.h>

#define DIMX 512
#define NHEADS 8
#define DH 64
#define MF 266            // real feature count
#define MP 272            // padded feature count (16-multiple)
#define NB 2
#define NSEQ 2048
#define NROWS (NB*NSEQ)   // 4096
#define NBH 16
#define CHK 64
#define NCH 32
#define EPSF 1e-4f
#define LDT 40            // LDS row stride (ushort) for gemm tiles: 80B, 16B-aligned, 2-way banks

typedef __attribute__((ext_vector_type(8))) short short8;
typedef __attribute__((ext_vector_type(4))) float f32x4;
typedef unsigned short ushort_t;

__device__ __forceinline__ unsigned fkey(float f){
    unsigned u = __float_as_uint(f);
    return (f < 0.0f) ? ~u : (u | 0x80000000u);
}
__device__ __forceinline__ float fdec(unsigned k){
    unsigned u = (k & 0x80000000u) ? (k & 0x7fffffffu) : ~k;
    return __uint_as_float(u);
}

// split fp32 a into bf16 hi + bf16 lo (RNE both): a ≈ hi + lo, residual ~2^-17|a|
__device__ __forceinline__ void bsplit(float a, ushort_t& h, ushort_t& l){
    unsigned u = __float_as_uint(a);
    unsigned r = (u + 0x7fffu + ((u >> 16) & 1u)) & 0xffff0000u;
    h = (ushort_t)(r >> 16);
    float res = a - __uint_as_float(r);
    unsigned v = __float_as_uint(res);
    unsigned r2 = v + 0x7fffu + ((v >> 16) & 1u);
    l = (ushort_t)(r2 >> 16);
}

// elementwise split: A fp32 [total4*4] -> H,L bf16
__global__ __launch_bounds__(256) void split_kernel(
    const float* __restrict__ A, ushort_t* __restrict__ H, ushort_t* __restrict__ L, int total4)
{
    int i = blockIdx.x * 256 + threadIdx.x;
    if (i >= total4) return;
    float4 f = ((const float4*)A)[i];
    ushort_t h0,h1,h2,h3,l0,l1,l2,l3;
    bsplit(f.x,h0,l0); bsplit(f.y,h1,l1); bsplit(f.z,h2,l2); bsplit(f.w,h3,l3);
    ushort4 hv = make_ushort4(h0,h1,h2,h3), lv = make_ushort4(l0,l1,l2,l3);
    ((ushort4*)H)[i] = hv;
    ((ushort4*)L)[i] = lv;
}

// W [K][N] fp32 -> Th,Tl [N][K] bf16 (transpose + split), 64x64 tiles
__global__ __launch_bounds__(256) void splitT_kernel(
    const float* __restrict__ W, ushort_t* __restrict__ Th, ushort_t* __restrict__ Tl,
    int K, int N)
{
    __shared__ ushort_t Sh[64][72], Sl[64][72];
    const int k0 = blockIdx.y * 64, n0 = blockIdx.x * 64;
    const int tid = threadIdx.x;
    {
        const int kk = tid >> 4, nq = (tid & 15) * 4;
        for (int p = 0; p < 4; p++) {
            int k = p*16 + kk;
            float4 f = *(const float4*)&W[(size_t)(k0 + k)*N + n0 + nq];
            ushort_t h, l;
            bsplit(f.x,h,l); Sh[nq+0][k]=h; Sl[nq+0][k]=l;
            bsplit(f.y,h,l); Sh[nq+1][k]=h; Sl[nq+1][k]=l;
            bsplit(f.z,h,l); Sh[nq+2][k]=h; Sl[nq+2][k]=l;
            bsplit(f.w,h,l); Sh[nq+3][k]=h; Sl[nq+3][k]=l;
        }
    }
    __syncthreads();
    {
        const int n = tid >> 2, ks = (tid & 3) * 16;
        for (int q = 0; q < 2; q++) {
            uint4 vh = *(const uint4*)&Sh[n][ks + q*8];
            uint4 vl = *(const uint4*)&Sl[n][ks + q*8];
            *(uint4*)&Th[(size_t)(n0 + n)*K + k0 + ks + q*8] = vh;
            *(uint4*)&Tl[(size_t)(n0 + n)*K + k0 + ks + q*8] = vl;
        }
    }
}

// C[M][N] = (Ah+Al)[M][K] @ (Bh+Bl)^T[N][K] (+bias) via 3x bf16 MFMA split.
// 128x128 tile, BK=32, 256 thr = 4 waves, each wave 64x64 (4x4 frags of 16x16x32).
__global__ __launch_bounds__(256) void gemm_bf16s(
    const ushort_t* __restrict__ Ah, const ushort_t* __restrict__ Al,
    const ushort_t* __restrict__ Bh, const ushort_t* __restrict__ Bl,
    const float* __restrict__ bias, float* __restrict__ C,
    int M, int N, int K)
{
    __shared__ ushort_t sAh[128*LDT], sAl[128*LDT], sBh[128*LDT], sBl[128*LDT];
    const int tid = threadIdx.x;
    const int m0 = blockIdx.y * 128, n0 = blockIdx.x * 128;
    const int lane = tid & 63, w = tid >> 6;
    const int wr = w >> 1, wc = w & 1;
    const int lr = lane & 15;
    const int lsu = (lane >> 4) * 8;        // k offset (ushort) of this lane's frag
    const int r = tid >> 1, sg = (tid & 1) * 16;   // staging: row, 16-bf16 segment
    const size_t gA = (size_t)(m0 + r)*K + sg;
    const size_t gB = (size_t)(n0 + r)*K + sg;

    f32x4 acc[4][4];
    #pragma unroll
    for (int i=0;i<4;i++)
        #pragma unroll
        for (int j=0;j<4;j++) acc[i][j] = (f32x4){0.f,0.f,0.f,0.f};

    for (int k0 = 0; k0 < K; k0 += 32) {
        uint4 a0 = *(const uint4*)&Ah[gA + k0];
        uint4 a1 = *(const uint4*)&Ah[gA + k0 + 8];
        uint4 a2 = *(const uint4*)&Al[gA + k0];
        uint4 a3 = *(const uint4*)&Al[gA + k0 + 8];
        uint4 b0 = *(const uint4*)&Bh[gB + k0];
        uint4 b1 = *(const uint4*)&Bh[gB + k0 + 8];
        uint4 b2 = *(const uint4*)&Bl[gB + k0];
        uint4 b3 = *(const uint4*)&Bl[gB + k0 + 8];
        __syncthreads();
        *(uint4*)&sAh[r*LDT + sg]     = a0;
        *(uint4*)&sAh[r*LDT + sg + 8] = a1;
        *(uint4*)&sAl[r*LDT + sg]     = a2;
        *(uint4*)&sAl[r*LDT + sg + 8] = a3;
        *(uint4*)&sBh[r*LDT + sg]     = b0;
        *(uint4*)&sBh[r*LDT + sg + 8] = b1;
        *(uint4*)&sBl[r*LDT + sg]     = b2;
        *(uint4*)&sBl[r*LDT + sg + 8] = b3;
        __syncthreads();
        short8 afh[4], afl[4], bfh[4], bfl[4];
        #pragma unroll
        for (int f = 0; f < 4; f++) {
            int ra = (wr*64 + f*16 + lr)*LDT + lsu;
            int rb = (wc*64 + f*16 + lr)*LDT + lsu;
            afh[f] = *(const short8*)&sAh[ra];
            afl[f] = *(const short8*)&sAl[ra];
            bfh[f] = *(const short8*)&sBh[rb];
            bfl[f] = *(const short8*)&sBl[rb];
        }
        #pragma unroll
        for (int i = 0; i < 4; i++)
            #pragma unroll
            for (int j = 0; j < 4; j++) {
                acc[i][j] = __builtin_amdgcn_mfma_f32_16x16x32_bf16(afh[i], bfh[j], acc[i][j], 0, 0, 0);
                acc[i][j] = __builtin_amdgcn_mfma_f32_16x16x32_bf16(afh[i], bfl[j], acc[i][j], 0, 0, 0);
                acc[i][j] = __builtin_amdgcn_mfma_f32_16x16x32_bf16(afl[i], bfh[j], acc[i][j], 0, 0, 0);
            }
    }
    // epilogue: D lane mapping col=lane&15, row=(lane>>4)*4+reg
    const int crow = (lane >> 4) * 4, ccol = lane & 15;
    #pragma unroll
    for (int i = 0; i < 4; i++) {
        #pragma unroll
        for (int j = 0; j < 4; j++) {
            int col = n0 + wc*64 + j*16 + ccol;
            float bb = bias ? bias[col] : 0.f;
            #pragma unroll
            for (int rr = 0; rr < 4; rr++) {
                int row = m0 + wr*64 + i*16 + crow + rr;
                C[(size_t)row*N + col] = acc[i][j][rr] + bb;
            }
        }
    }
}

// Feature map dash = (nrm*data) @ proj^T for a 64-row tile of one (b,h).
template<bool IS_Q>
__global__ __launch_bounds__(256) void feat_kernel(
    const float* __restrict__ qkv, const float* __restrict__ proj,
    float* __restrict__ outp, float* __restrict__ diag_out,
    unsigned* __restrict__ gmax, int coff, float nrm, float ratio)
{
    __shared__ float As[64][68];     // As[k][row]
    __shared__ float Bs[16][MP+1];   // Bs[kk][m] per k-step
    const int tid = threadIdx.x;
    const int tx = tid & 15, ty = tid >> 4;
    const int bh = blockIdx.y, b = bh >> 3, h = bh & 7;
    const int n0 = blockIdx.x * 64;
    {
        const int r = tid & 63, lq = tid >> 6;
        const float* src = &qkv[(size_t)(b*NSEQ + n0 + r)*(3*DIMX) + coff + h*DH];
        #pragma unroll
        for (int qq = 0; qq < 4; qq++) {
            int c = lq*16 + qq*4;
            float4 f = *(const float4*)&src[c];
            As[c+0][r]=f.x; As[c+1][r]=f.y; As[c+2][r]=f.z; As[c+3][r]=f.w;
        }
    }
    float dash[4][17];
    #pragma unroll
    for (int i=0;i<4;i++)
        #pragma unroll
        for (int j=0;j<17;j++) dash[i][j] = 0.f;
    float dsq[4] = {0.f,0.f,0.f,0.f};
    for (int s = 0; s < 4; s++) {
        __syncthreads();
        for (int idx = tid; idx < MP*4; idx += 256) {
            int m = idx >> 2, qq = idx & 3;
            float4 f = make_float4(0.f,0.f,0.f,0.f);
            if (m < MF) f = *(const float4*)&proj[m*DH + s*16 + qq*4];
            Bs[qq*4+0][m]=f.x; Bs[qq*4+1][m]=f.y; Bs[qq*4+2][m]=f.z; Bs[qq*4+3][m]=f.w;
        }
        __syncthreads();
        #pragma unroll
        for (int kk = 0; kk < 16; kk++) {
            float4 a = *(const float4*)&As[s*16+kk][ty*4];
            float ar[4] = {a.x,a.y,a.z,a.w};
            #pragma unroll
            for (int i=0;i<4;i++) dsq[i] = fmaf(ar[i], ar[i], dsq[i]);
            #pragma unroll
            for (int jj = 0; jj < 17; jj++) {
                float bv = Bs[kk][tx + 16*jj];
                #pragma unroll
                for (int i=0;i<4;i++) dash[i][jj] = fmaf(ar[i], bv, dash[i][jj]);
            }
        }
    }
    const size_t rbase = (size_t)bh*NSEQ + n0 + ty*4;
    if (IS_Q) {
        #pragma unroll
        for (int i=0;i<4;i++){
            float diag = 0.0625f * dsq[i];
            float mx = -1e30f;
            #pragma unroll
            for (int jj=0;jj<17;jj++){
                dash[i][jj] *= nrm;
                if (tx + 16*jj < MF) mx = fmaxf(mx, dash[i][jj]);
            }
            #pragma unroll
            for (int o=1;o<16;o<<=1) mx = fmaxf(mx, __shfl_xor(mx, o, 64));
            float* orow = &outp[(rbase + i)*MP];
            #pragma unroll
            for (int jj=0;jj<17;jj++){
                int m = tx + 16*jj;
                float v = (m < MF) ? ratio*(expf(dash[i][jj] - diag - mx) + EPSF) : 0.f;
                orow[m] = v;
            }
        }
    } else {
        float wmax = -1e30f;
        #pragma unroll
        for (int i=0;i<4;i++){
            float diag = 0.0625f * dsq[i];
            if (tx == 0) diag_out[rbase + i] = diag;
            float* orow = &outp[(rbase + i)*MP];
            #pragma unroll
            for (int jj=0;jj<17;jj++){
                float d = dash[i][jj] * nrm;
                int m = tx + 16*jj;
                orow[m] = d;
                if (m < MF) wmax = fmaxf(wmax, d);
            }
        }
        #pragma unroll
        for (int o=1;o<64;o<<=1) wmax = fmaxf(wmax, __shfl_xor(wmax, o, 64));
        if ((tid & 63) == 0) atomicMax(gmax, fkey(wmax));
    }
}

__global__ __launch_bounds__(256) void kexp_kernel(
    float* __restrict__ kp, const float* __restrict__ diagk,
    const unsigned* __restrict__ gmax, float ratio)
{
    unsigned idx4 = (blockIdx.x * 256u + threadIdx.x) * 4u;
    if (idx4 >= (unsigned)NBH*NSEQ*MP) return;
    const float stab = fdec(*gmax);
    int m = idx4 % MP;
    unsigned row = idx4 / MP;
    float dg = diagk[row];
    float4 v = *(float4*)&kp[idx4];
    float r[4] = {v.x,v.y,v.z,v.w};
    #pragma unroll
    for (int j = 0; j < 4; j++)
        r[j] = (m + j < MF) ? ratio * (expf(r[j] - dg - stab) + EPSF) : 0.f;
    *(float4*)&kp[idx4] = make_float4(r[0],r[1],r[2],r[3]);
}

// Per (b,h,chunk): KV[m][d] = K_c^T V_c, Ksum[m] = col-sums of K_c
__global__ __launch_bounds__(320) void chunk_sums_kernel(
    const float* __restrict__ kp, const float* __restrict__ qkv,
    float* __restrict__ ckv, float* __restrict__ cksum)
{
    __shared__ float vs[CHK][DH];
    const int tid = threadIdx.x;
    const int c = blockIdx.x, bh = blockIdx.y, b = bh >> 3, h = bh & 7;
    for (int idx = tid; idx < CHK*16; idx += 320) {
        int i = idx >> 4, q = idx & 15;
        *(float4*)&vs[i][q*4] =
            *(const float4*)&qkv[(size_t)(b*NSEQ + c*CHK + i)*(3*DIMX) + 2*DIMX + h*DH + q*4];
    }
    __syncthreads();
    if (tid >= 272) return;
    const int mg = tid % 68, dg = tid / 68;   // m block of 4, d block of 16
    float acc[4][16] = {};
    float ks[4] = {0.f,0.f,0.f,0.f};
    const size_t kbase = (size_t)(bh*NSEQ + c*CHK)*MP + mg*4;
    for (int i = 0; i < CHK; i++) {
        float4 kv = *(const float4*)&kp[kbase + (size_t)i*MP];
        float kr[4] = {kv.x,kv.y,kv.z,kv.w};
        if (dg == 0) { ks[0]+=kr[0]; ks[1]+=kr[1]; ks[2]+=kr[2]; ks[3]+=kr[3]; }
        #pragma unroll
        for (int t = 0; t < 4; t++) {
            float4 vv = *(const float4*)&vs[i][dg*16 + t*4];
            float vr[4] = {vv.x,vv.y,vv.z,vv.w};
            #pragma unroll
            for (int mi=0;mi<4;mi++){
                acc[mi][t*4+0] = fmaf(kr[mi], vr[0], acc[mi][t*4+0]);
                acc[mi][t*4+1] = fmaf(kr[mi], vr[1], acc[mi][t*4+1]);
                acc[mi][t*4+2] = fmaf(kr[mi], vr[2], acc[mi][t*4+2]);
                acc[mi][t*4+3] = fmaf(kr[mi], vr[3], acc[mi][t*4+3]);
            }
        }
    }
    const size_t obase = ((size_t)(bh*NCH + c)*MP + mg*4)*DH + dg*16;
    #pragma unroll
    for (int mi=0;mi<4;mi++)
        #pragma unroll
        for (int t=0;t<4;t++)
            *(float4*)&ckv[obase + (size_t)mi*DH + t*4] =
                make_float4(acc[mi][t*4], acc[mi][t*4+1], acc[mi][t*4+2], acc[mi][t*4+3]);
    if (dg == 0) {
        #pragma unroll
        for (int mi=0;mi<4;mi++)
            cksum[(size_t)(bh*NCH + c)*MP + mg*4 + mi] = ks[mi];
    }
}

__global__ __launch_bounds__(256) void prefix_kv_kernel(float* __restrict__ ckv)
{
    const int bh = blockIdx.y;
    const int md = blockIdx.x * 256 + threadIdx.x;  // < MP*DH = 17408
    float run = 0.f;
    #pragma unroll
    for (int c = 0; c < NCH; c++) {
        size_t idx = (size_t)(bh*NCH + c)*MP*DH + md;
        float v = ckv[idx];
        ckv[idx] = run;
        run += v;
    }
}

__global__ __launch_bounds__(320) void prefix_ksum_kernel(float* __restrict__ cksum)
{
    const int bh = blockIdx.x;
    const int m = threadIdx.x;
    if (m >= MP) return;
    float run = 0.f;
    #pragma unroll
    for (int c = 0; c < NCH; c++) {
        size_t idx = (size_t)(bh*NCH + c)*MP + m;
        float v = cksum[idx];
        cksum[idx] = run;
        run += v;
    }
}

// q'_nm = qp_nm / (exclusive-chunk-prefix + within-chunk inclusive cumsum of kp)
__global__ __launch_bounds__(320) void qprime_kernel(
    float* __restrict__ qp, const float* __restrict__ kp, const float* __restrict__ cksum)
{
    const int c = blockIdx.x, bh = blockIdx.y;
    const int m = threadIdx.x;
    if (m >= MP) return;
    float run = cksum[(size_t)(bh*NCH + c)*MP + m];
    size_t base = (size_t)(bh*NSEQ + c*CHK)*MP + m;
    for (int i = 0; i < CHK; i++) {
        size_t idx = base + (size_t)i*MP;
        run += kp[idx];
        float q = qp[idx];
        qp[idx] = (m < MF) ? q / run : 0.f;
    }
}

// Per (b,h,chunk of 64): out = Q'@S + tril(Q'K^T)@V ; writes aout as bf16 hi/lo
__global__ __launch_bounds__(256) void attn_kernel(
    const float* __restrict__ qp, const float* __restrict__ kp,
    const float* __restrict__ qkv, const float* __restrict__ ckv,
    ushort_t* __restrict__ aout_h, ushort_t* __restrict__ aout_l)
{
    __shared__ float Qs[16][68];
    __shared__ float Ks[16][68];
    __shared__ float Ss[16][68];
    __shared__ float Vs[CHK][68];
    __shared__ float P[CHK][76];   // stride 76: row-step = 16 banks (2-way, free)
    const int tid = threadIdx.x, tx = tid & 15, ty = tid >> 4;
    const int c = blockIdx.x, bh = blockIdx.y, b = bh >> 3, hh = bh & 7;
    const size_t rowg = (size_t)bh*NSEQ + c*CHK;   // qp/kp row base
    const size_t rowx = (size_t)b*NSEQ + c*CHK;    // qkv/aout row base

    // load V chunk once
    for (int idx = tid; idx < CHK*16; idx += 256) {
        int i = idx >> 4, q = idx & 15;
        *(float4*)&Vs[i][q*4] =
            *(const float4*)&qkv[(rowx + i)*(3*DIMX) + 2*DIMX + hh*DH + q*4];
    }

    float accP[4][4] = {};
    float accO[4][4] = {};
    const int ldi = tid >> 2, ldq = tid & 3;   // 64 rows x 4 quads
    const int smm = tid >> 4, smq = tid & 15;  // 16 rows x 16 quads
    for (int m0 = 0; m0 < MP; m0 += 16) {
        __syncthreads();
        {
            float4 f = *(const float4*)&qp[(rowg + ldi)*MP + m0 + ldq*4];
            Qs[ldq*4+0][ldi]=f.x; Qs[ldq*4+1][ldi]=f.y; Qs[ldq*4+2][ldi]=f.z; Qs[ldq*4+3][ldi]=f.w;
            float4 g = *(const float4*)&kp[(rowg + ldi)*MP + m0 + ldq*4];
            Ks[ldq*4+0][ldi]=g.x; Ks[ldq*4+1][ldi]=g.y; Ks[ldq*4+2][ldi]=g.z; Ks[ldq*4+3][ldi]=g.w;
            *(float4*)&Ss[smm][smq*4] =
                *(const float4*)&ckv[((size_t)(bh*NCH + c)*MP + m0 + smm)*DH + smq*4];
        }
        __syncthreads();
        #pragma unroll
        for (int kk = 0; kk < 16; kk++) {
            float4 a = *(const float4*)&Qs[kk][ty*4];
            float4 bk = *(const float4*)&Ks[kk][tx*4];
            float4 bs = *(const float4*)&Ss[kk][tx*4];
            float ar[4] = {a.x,a.y,a.z,a.w};
            float kr[4] = {bk.x,bk.y,bk.z,bk.w};
            float sr[4] = {bs.x,bs.y,bs.z,bs.w};
            #pragma unroll
            for (int i=0;i<4;i++)
                #pragma unroll
                for (int j=0;j<4;j++) {
                    accP[i][j] = fmaf(ar[i], kr[j], accP[i][j]);
                    accO[i][j] = fmaf(ar[i], sr[j], accO[i][j]);
                }
        }
    }
    // write masked P
    #pragma unroll
    for (int i=0;i<4;i++){
        int r = ty*4+i;
        float4 o;
        o.x = (tx*4+0 <= r) ? accP[i][0] : 0.f;
        o.y = (tx*4+1 <= r) ? accP[i][1] : 0.f;
        o.z = (tx*4+2 <= r) ? accP[i][2] : 0.f;
        o.w = (tx*4+3 <= r) ? accP[i][3] : 0.f;
        *(float4*)&P[r][tx*4] = o;
    }
    __syncthreads();
    // O += P @ V
    #pragma unroll 4
    for (int kk = 0; kk < CHK; kk++) {
        float4 vv = *(const float4*)&Vs[kk][tx*4];
        float vr[4] = {vv.x,vv.y,vv.z,vv.w};
        #pragma unroll
        for (int i=0;i<4;i++){
            float a = P[ty*4+i][kk];
            accO[i][0] = fmaf(a, vr[0], accO[i][0]);
            accO[i][1] = fmaf(a, vr[1], accO[i][1]);
            accO[i][2] = fmaf(a, vr[2], accO[i][2]);
            accO[i][3] = fmaf(a, vr[3], accO[i][3]);
        }
    }
    #pragma unroll
    for (int i=0;i<4;i++){
        ushort_t h0,h1,h2,h3,l0,l1,l2,l3;
        bsplit(accO[i][0],h0,l0); bsplit(accO[i][1],h1,l1);
        bsplit(accO[i][2],h2,l2); bsplit(accO[i][3],h3,l3);
        size_t o = (rowx + ty*4 + i)*DIMX + hh*DH + tx*4;
        *(ushort4*)&aout_h[o] = make_ushort4(h0,h1,h2,h3);
        *(ushort4*)&aout_l[o] = make_ushort4(l0,l1,l2,l3);
    }
}

extern "C" void kernel_launch(void* const* d_in, const int* in_sizes, int n_in,
                              void* d_out, int out_size, void* d_ws, size_t ws_size,
                              hipStream_t stream)
{
    (void)in_sizes; (void)n_in; (void)out_size; (void)ws_size;
    const float* x     = (const float*)d_in[0];
    const float* w_qkv = (const float*)d_in[1];
    const float* w_out = (const float*)d_in[2];
    const float* b_out = (const float*)d_in[3];
    const float* proj  = (const float*)d_in[4];
    float* out = (float*)d_out;

    char* ws = (char*)d_ws;
    size_t off = 0;
    auto alloc = [&](size_t bytes) -> char* {
        char* p = ws + off;
        off += (bytes + 255) & ~(size_t)255;
        return p;
    };
    float* qkv       = (float*)alloc((size_t)NROWS*3*DIMX*sizeof(float));     // 25.2 MB
    float* qp        = (float*)alloc((size_t)NBH*NSEQ*MP*sizeof(float));      // 35.7 MB
    float* kp        = (float*)alloc((size_t)NBH*NSEQ*MP*sizeof(float));      // 35.7 MB
    float* diagk     = (float*)alloc((size_t)NBH*NSEQ*sizeof(float));
    unsigned* gmax   = (unsigned*)alloc(256);
    float* ckv       = (float*)alloc((size_t)NBH*NCH*MP*DH*sizeof(float));    // 35.7 MB
    float* cksum     = (float*)alloc((size_t)NBH*NCH*MP*sizeof(float));
    ushort_t* xs_h   = (ushort_t*)alloc((size_t)NROWS*DIMX*sizeof(ushort_t)); // 4.2 MB (aliased: aout_h)
    ushort_t* xs_l   = (ushort_t*)alloc((size_t)NROWS*DIMX*sizeof(ushort_t)); // 4.2 MB (aliased: aout_l)
    ushort_t* wqt_h  = (ushort_t*)alloc((size_t)(3*DIMX)*DIMX*sizeof(ushort_t));
    ushort_t* wqt_l  = (ushort_t*)alloc((size_t)(3*DIMX)*DIMX*sizeof(ushort_t));
    ushort_t* wot_h  = (ushort_t*)alloc((size_t)DIMX*DIMX*sizeof(ushort_t));
    ushort_t* wot_l  = (ushort_t*)alloc((size_t)DIMX*DIMX*sizeof(ushort_t));
    // xs_h/xs_l are consumed by the qkv GEMM (dispatch 4) and reused as aout (dispatch 10+)
    ushort_t* aout_h = xs_h;
    ushort_t* aout_l = xs_l;

    const float nrm   = (float)pow(64.0, -0.25);   // 2^-1.5
    const float ratio = (float)(1.0 / sqrt(266.0));

    hipMemsetAsync(gmax, 0, sizeof(unsigned), stream);
    // input splits
    split_kernel<<<dim3((NROWS*DIMX/4 + 255)/256), 256, 0, stream>>>(x, xs_h, xs_l, NROWS*DIMX/4);
    splitT_kernel<<<dim3(3*DIMX/64, DIMX/64), 256, 0, stream>>>(w_qkv, wqt_h, wqt_l, DIMX, 3*DIMX);
    splitT_kernel<<<dim3(DIMX/64, DIMX/64), 256, 0, stream>>>(w_out, wot_h, wot_l, DIMX, DIMX);
    // qkv = x @ w_qkv  (split-bf16 MFMA)
    gemm_bf16s<<<dim3(3*DIMX/128, NROWS/128), 256, 0, stream>>>(
        xs_h, xs_l, wqt_h, wqt_l, nullptr, qkv, NROWS, 3*DIMX, DIMX);
    // feature maps
    feat_kernel<true ><<<dim3(32, 16), 256, 0, stream>>>(qkv, proj, qp, nullptr, nullptr, 0, nrm, ratio);
    feat_kernel<false><<<dim3(32, 16), 256, 0, stream>>>(qkv, proj, kp, diagk, gmax, DIMX, nrm, ratio);
    kexp_kernel<<<dim3((NBH*NSEQ*MP)/1024), 256, 0, stream>>>(kp, diagk, gmax, ratio);
    // chunk scan (C=64)
    chunk_sums_kernel<<<dim3(NCH, NBH), 320, 0, stream>>>(kp, qkv, ckv, cksum);
    prefix_kv_kernel<<<dim3(68, NBH), 256, 0, stream>>>(ckv);
    prefix_ksum_kernel<<<dim3(NBH), 320, 0, stream>>>(cksum);
    qprime_kernel<<<dim3(NCH, NBH), 320, 0, stream>>>(qp, kp, cksum);
    attn_kernel<<<dim3(NCH, NBH), 256, 0, stream>>>(qp, kp, qkv, ckv, aout_h, aout_l);
    // out = aout @ w_out + b_out  (split-bf16 MFMA)
    gemm_bf16s<<<dim3(DIMX/128, NROWS/128), 256, 0, stream>>>(
        aout_h, aout_l, wot_h, wot_l, b_out, out, NROWS, DIMX, DIMX);
}

// Round 7
// 268.774 us; speedup vs baseline: 1.6267x; 1.0976x over previous
//
#include <hip/hip_runtime.h>
#include <math.h>

#define DIMX 512
#define NHEADS 8
#define DH 64
#define MF 266            // real feature count
#define MP 272            // padded feature count (16-multiple)
#define MPS 288           // padded stride for split bf16 arrays (32-multiple)
#define NB 2
#define NSEQ 2048
#define NROWS (NB*NSEQ)   // 4096
#define NBH 16
#define CHK 64
#define NCH 32
#define EPSF 1e-4f
#define LDT 40            // LDS row stride (ushort) for gemm tiles
#define LDP 72            // LDS row stride (ushort) for P/VT tiles (144B, 16B-aligned)

typedef __attribute__((ext_vector_type(8))) short short8;
typedef __attribute__((ext_vector_type(4))) float f32x4;
typedef unsigned short ushort_t;

__device__ __forceinline__ unsigned fkey(float f){
    unsigned u = __float_as_uint(f);
    return (f < 0.0f) ? ~u : (u | 0x80000000u);
}
__device__ __forceinline__ float fdec(unsigned k){
    unsigned u = (k & 0x80000000u) ? (k & 0x7fffffffu) : ~k;
    return __uint_as_float(u);
}
__device__ __forceinline__ float b2f(ushort_t u){
    return __uint_as_float(((unsigned)u) << 16);
}

// split fp32 a into bf16 hi + bf16 lo (RNE both): a ≈ hi + lo, residual ~2^-17|a|
__device__ __forceinline__ void bsplit(float a, ushort_t& h, ushort_t& l){
    unsigned u = __float_as_uint(a);
    unsigned r = (u + 0x7fffu + ((u >> 16) & 1u)) & 0xffff0000u;
    h = (ushort_t)(r >> 16);
    float res = a - __uint_as_float(r);
    unsigned v = __float_as_uint(res);
    unsigned r2 = v + 0x7fffu + ((v >> 16) & 1u);
    l = (ushort_t)(r2 >> 16);
}

// elementwise split: A fp32 [total4*4] -> H,L bf16
__global__ __launch_bounds__(256) void split_kernel(
    const float* __restrict__ A, ushort_t* __restrict__ H, ushort_t* __restrict__ L, int total4)
{
    int i = blockIdx.x * 256 + threadIdx.x;
    if (i >= total4) return;
    float4 f = ((const float4*)A)[i];
    ushort_t h0,h1,h2,h3,l0,l1,l2,l3;
    bsplit(f.x,h0,l0); bsplit(f.y,h1,l1); bsplit(f.z,h2,l2); bsplit(f.w,h3,l3);
    ((ushort4*)H)[i] = make_ushort4(h0,h1,h2,h3);
    ((ushort4*)L)[i] = make_ushort4(l0,l1,l2,l3);
}

// W [K][N] fp32 -> Th,Tl [N][K] bf16 (transpose + split), 64x64 tiles
__global__ __launch_bounds__(256) void splitT_kernel(
    const float* __restrict__ W, ushort_t* __restrict__ Th, ushort_t* __restrict__ Tl,
    int K, int N)
{
    __shared__ ushort_t Sh[64][72], Sl[64][72];
    const int k0 = blockIdx.y * 64, n0 = blockIdx.x * 64;
    const int tid = threadIdx.x;
    {
        const int kk = tid >> 4, nq = (tid & 15) * 4;
        for (int p = 0; p < 4; p++) {
            int k = p*16 + kk;
            float4 f = *(const float4*)&W[(size_t)(k0 + k)*N + n0 + nq];
            ushort_t h, l;
            bsplit(f.x,h,l); Sh[nq+0][k]=h; Sl[nq+0][k]=l;
            bsplit(f.y,h,l); Sh[nq+1][k]=h; Sl[nq+1][k]=l;
            bsplit(f.z,h,l); Sh[nq+2][k]=h; Sl[nq+2][k]=l;
            bsplit(f.w,h,l); Sh[nq+3][k]=h; Sl[nq+3][k]=l;
        }
    }
    __syncthreads();
    {
        const int n = tid >> 2, ks = (tid & 3) * 16;
        for (int q = 0; q < 2; q++) {
            uint4 vh = *(const uint4*)&Sh[n][ks + q*8];
            uint4 vl = *(const uint4*)&Sl[n][ks + q*8];
            *(uint4*)&Th[(size_t)(n0 + n)*K + k0 + ks + q*8] = vh;
            *(uint4*)&Tl[(size_t)(n0 + n)*K + k0 + ks + q*8] = vl;
        }
    }
}

// C[M][N] = (Ah+Al)[M][K] @ (Bh+Bl)^T[N][K] (+bias) via 3x bf16 MFMA split.
__global__ __launch_bounds__(256) void gemm_bf16s(
    const ushort_t* __restrict__ Ah, const ushort_t* __restrict__ Al,
    const ushort_t* __restrict__ Bh, const ushort_t* __restrict__ Bl,
    const float* __restrict__ bias, float* __restrict__ C,
    int M, int N, int K)
{
    __shared__ ushort_t sAh[128*LDT], sAl[128*LDT], sBh[128*LDT], sBl[128*LDT];
    const int tid = threadIdx.x;
    const int m0 = blockIdx.y * 128, n0 = blockIdx.x * 128;
    const int lane = tid & 63, w = tid >> 6;
    const int wr = w >> 1, wc = w & 1;
    const int lr = lane & 15;
    const int lsu = (lane >> 4) * 8;
    const int r = tid >> 1, sg = (tid & 1) * 16;
    const size_t gA = (size_t)(m0 + r)*K + sg;
    const size_t gB = (size_t)(n0 + r)*K + sg;

    f32x4 acc[4][4];
    #pragma unroll
    for (int i=0;i<4;i++)
        #pragma unroll
        for (int j=0;j<4;j++) acc[i][j] = (f32x4){0.f,0.f,0.f,0.f};

    for (int k0 = 0; k0 < K; k0 += 32) {
        uint4 a0 = *(const uint4*)&Ah[gA + k0];
        uint4 a1 = *(const uint4*)&Ah[gA + k0 + 8];
        uint4 a2 = *(const uint4*)&Al[gA + k0];
        uint4 a3 = *(const uint4*)&Al[gA + k0 + 8];
        uint4 b0 = *(const uint4*)&Bh[gB + k0];
        uint4 b1 = *(const uint4*)&Bh[gB + k0 + 8];
        uint4 b2 = *(const uint4*)&Bl[gB + k0];
        uint4 b3 = *(const uint4*)&Bl[gB + k0 + 8];
        __syncthreads();
        *(uint4*)&sAh[r*LDT + sg]     = a0;
        *(uint4*)&sAh[r*LDT + sg + 8] = a1;
        *(uint4*)&sAl[r*LDT + sg]     = a2;
        *(uint4*)&sAl[r*LDT + sg + 8] = a3;
        *(uint4*)&sBh[r*LDT + sg]     = b0;
        *(uint4*)&sBh[r*LDT + sg + 8] = b1;
        *(uint4*)&sBl[r*LDT + sg]     = b2;
        *(uint4*)&sBl[r*LDT + sg + 8] = b3;
        __syncthreads();
        short8 afh[4], afl[4], bfh[4], bfl[4];
        #pragma unroll
        for (int f = 0; f < 4; f++) {
            int ra = (wr*64 + f*16 + lr)*LDT + lsu;
            int rb = (wc*64 + f*16 + lr)*LDT + lsu;
            afh[f] = *(const short8*)&sAh[ra];
            afl[f] = *(const short8*)&sAl[ra];
            bfh[f] = *(const short8*)&sBh[rb];
            bfl[f] = *(const short8*)&sBl[rb];
        }
        #pragma unroll
        for (int i = 0; i < 4; i++)
            #pragma unroll
            for (int j = 0; j < 4; j++) {
                acc[i][j] = __builtin_amdgcn_mfma_f32_16x16x32_bf16(afh[i], bfh[j], acc[i][j], 0, 0, 0);
                acc[i][j] = __builtin_amdgcn_mfma_f32_16x16x32_bf16(afh[i], bfl[j], acc[i][j], 0, 0, 0);
                acc[i][j] = __builtin_amdgcn_mfma_f32_16x16x32_bf16(afl[i], bfh[j], acc[i][j], 0, 0, 0);
            }
    }
    const int crow = (lane >> 4) * 4, ccol = lane & 15;
    #pragma unroll
    for (int i = 0; i < 4; i++) {
        #pragma unroll
        for (int j = 0; j < 4; j++) {
            int col = n0 + wc*64 + j*16 + ccol;
            float bb = bias ? bias[col] : 0.f;
            #pragma unroll
            for (int rr = 0; rr < 4; rr++) {
                int row = m0 + wr*64 + i*16 + crow + rr;
                C[(size_t)row*N + col] = acc[i][j][rr] + bb;
            }
        }
    }
}

// Feature map dash = (nrm*data) @ proj^T for a 64-row tile of one (b,h).
// IS_Q: writes qp split bf16 hi/lo (stride MPS). !IS_Q: writes raw dash fp32 + diag + global max.
template<bool IS_Q>
__global__ __launch_bounds__(256) void feat_kernel(
    const float* __restrict__ qkv, const float* __restrict__ proj,
    float* __restrict__ dashout, ushort_t* __restrict__ oh, ushort_t* __restrict__ ol,
    float* __restrict__ diag_out, unsigned* __restrict__ gmax,
    int coff, float nrm, float ratio)
{
    __shared__ float As[64][68];     // As[k][row]
    __shared__ float Bs[16][MP+1];   // Bs[kk][m] per k-step
    const int tid = threadIdx.x;
    const int tx = tid & 15, ty = tid >> 4;
    const int bh = blockIdx.y, b = bh >> 3, h = bh & 7;
    const int n0 = blockIdx.x * 64;
    {
        const int r = tid & 63, lq = tid >> 6;
        const float* src = &qkv[(size_t)(b*NSEQ + n0 + r)*(3*DIMX) + coff + h*DH];
        #pragma unroll
        for (int qq = 0; qq < 4; qq++) {
            int c = lq*16 + qq*4;
            float4 f = *(const float4*)&src[c];
            As[c+0][r]=f.x; As[c+1][r]=f.y; As[c+2][r]=f.z; As[c+3][r]=f.w;
        }
    }
    float dash[4][17];
    #pragma unroll
    for (int i=0;i<4;i++)
        #pragma unroll
        for (int j=0;j<17;j++) dash[i][j] = 0.f;
    float dsq[4] = {0.f,0.f,0.f,0.f};
    for (int s = 0; s < 4; s++) {
        __syncthreads();
        for (int idx = tid; idx < MP*4; idx += 256) {
            int m = idx >> 2, qq = idx & 3;
            float4 f = make_float4(0.f,0.f,0.f,0.f);
            if (m < MF) f = *(const float4*)&proj[m*DH + s*16 + qq*4];
            Bs[qq*4+0][m]=f.x; Bs[qq*4+1][m]=f.y; Bs[qq*4+2][m]=f.z; Bs[qq*4+3][m]=f.w;
        }
        __syncthreads();
        #pragma unroll
        for (int kk = 0; kk < 16; kk++) {
            float4 a = *(const float4*)&As[s*16+kk][ty*4];
            float ar[4] = {a.x,a.y,a.z,a.w};
            #pragma unroll
            for (int i=0;i<4;i++) dsq[i] = fmaf(ar[i], ar[i], dsq[i]);
            #pragma unroll
            for (int jj = 0; jj < 17; jj++) {
                float bv = Bs[kk][tx + 16*jj];
                #pragma unroll
                for (int i=0;i<4;i++) dash[i][jj] = fmaf(ar[i], bv, dash[i][jj]);
            }
        }
    }
    const size_t rbase = (size_t)bh*NSEQ + n0 + ty*4;
    if (IS_Q) {
        #pragma unroll
        for (int i=0;i<4;i++){
            float diag = 0.0625f * dsq[i];
            float mx = -1e30f;
            #pragma unroll
            for (int jj=0;jj<17;jj++){
                dash[i][jj] *= nrm;
                if (tx + 16*jj < MF) mx = fmaxf(mx, dash[i][jj]);
            }
            #pragma unroll
            for (int o=1;o<16;o<<=1) mx = fmaxf(mx, __shfl_xor(mx, o, 64));
            ushort_t* orh = &oh[(rbase + i)*MPS];
            ushort_t* orl = &ol[(rbase + i)*MPS];
            #pragma unroll
            for (int jj=0;jj<17;jj++){
                int m = tx + 16*jj;
                float v = (m < MF) ? ratio*(expf(dash[i][jj] - diag - mx) + EPSF) : 0.f;
                ushort_t hh2, ll2;
                bsplit(v, hh2, ll2);
                orh[m] = hh2; orl[m] = ll2;
            }
        }
    } else {
        float wmax = -1e30f;
        #pragma unroll
        for (int i=0;i<4;i++){
            float diag = 0.0625f * dsq[i];
            if (tx == 0) diag_out[rbase + i] = diag;
            float* orow = &dashout[(rbase + i)*MP];
            #pragma unroll
            for (int jj=0;jj<17;jj++){
                float d = dash[i][jj] * nrm;
                int m = tx + 16*jj;
                orow[m] = d;
                if (m < MF) wmax = fmaxf(wmax, d);
            }
        }
        #pragma unroll
        for (int o=1;o<64;o<<=1) wmax = fmaxf(wmax, __shfl_xor(wmax, o, 64));
        if ((tid & 63) == 0) atomicMax(gmax, fkey(wmax));
    }
}

// k = ratio*(exp(dash - diag - stab) + eps) -> split bf16 hi/lo (stride MPS, zero tail)
__global__ __launch_bounds__(256) void kexp_kernel(
    const float* __restrict__ dash, const float* __restrict__ diagk,
    const unsigned* __restrict__ gmax,
    ushort_t* __restrict__ kph, ushort_t* __restrict__ kpl, float ratio)
{
    unsigned gid = blockIdx.x * 256u + threadIdx.x;
    if (gid >= (unsigned)NBH*NSEQ*(MPS/4)) return;
    unsigned row = gid / (MPS/4);
    int mq = (int)(gid % (MPS/4)) * 4;
    ushort4 h4 = make_ushort4(0,0,0,0), l4 = make_ushort4(0,0,0,0);
    if (mq < MP) {
        const float stab = fdec(*gmax);
        float dg = diagk[row];
        float4 v = *(const float4*)&dash[(size_t)row*MP + mq];
        float r[4] = {v.x,v.y,v.z,v.w};
        ushort_t hh[4], ll[4];
        #pragma unroll
        for (int j = 0; j < 4; j++) {
            float kv = (mq + j < MF) ? ratio * (expf(r[j] - dg - stab) + EPSF) : 0.f;
            bsplit(kv, hh[j], ll[j]);
        }
        h4 = make_ushort4(hh[0],hh[1],hh[2],hh[3]);
        l4 = make_ushort4(ll[0],ll[1],ll[2],ll[3]);
    }
    *(ushort4*)&kph[(size_t)row*MPS + mq] = h4;
    *(ushort4*)&kpl[(size_t)row*MPS + mq] = l4;
}

// Per (b,h,chunk): ckvT[d][m] = (K_c^T V_c)^T, cksum[m] = col-sums of K_c
__global__ __launch_bounds__(320) void chunk_sums_kernel(
    const ushort_t* __restrict__ kph, const ushort_t* __restrict__ kpl,
    const float* __restrict__ qkv,
    float* __restrict__ ckvT, float* __restrict__ cksum)
{
    __shared__ float vs[CHK][DH];
    const int tid = threadIdx.x;
    const int c = blockIdx.x, bh = blockIdx.y, b = bh >> 3, h = bh & 7;
    for (int idx = tid; idx < CHK*16; idx += 320) {
        int i = idx >> 4, q = idx & 15;
        *(float4*)&vs[i][q*4] =
            *(const float4*)&qkv[(size_t)(b*NSEQ + c*CHK + i)*(3*DIMX) + 2*DIMX + h*DH + q*4];
    }
    __syncthreads();
    if (tid >= 272) return;
    const int mg = tid % 68, dg = tid / 68;   // m block of 4, d block of 16
    float acc[4][16] = {};
    float ks[4] = {0.f,0.f,0.f,0.f};
    const size_t kbase = (size_t)(bh*NSEQ + c*CHK)*MPS + mg*4;
    for (int i = 0; i < CHK; i++) {
        ushort4 kh = *(const ushort4*)&kph[kbase + (size_t)i*MPS];
        ushort4 kl = *(const ushort4*)&kpl[kbase + (size_t)i*MPS];
        float kr[4] = {b2f(kh.x)+b2f(kl.x), b2f(kh.y)+b2f(kl.y),
                       b2f(kh.z)+b2f(kl.z), b2f(kh.w)+b2f(kl.w)};
        if (dg == 0) { ks[0]+=kr[0]; ks[1]+=kr[1]; ks[2]+=kr[2]; ks[3]+=kr[3]; }
        #pragma unroll
        for (int t = 0; t < 4; t++) {
            float4 vv = *(const float4*)&vs[i][dg*16 + t*4];
            float vr[4] = {vv.x,vv.y,vv.z,vv.w};
            #pragma unroll
            for (int mi=0;mi<4;mi++){
                acc[mi][t*4+0] = fmaf(kr[mi], vr[0], acc[mi][t*4+0]);
                acc[mi][t*4+1] = fmaf(kr[mi], vr[1], acc[mi][t*4+1]);
                acc[mi][t*4+2] = fmaf(kr[mi], vr[2], acc[mi][t*4+2]);
                acc[mi][t*4+3] = fmaf(kr[mi], vr[3], acc[mi][t*4+3]);
            }
        }
    }
    // transposed store: ckvT[(bh,c)][d][m], coalesced float4 along m
    const size_t tbase = (size_t)(bh*NCH + c)*64;
    #pragma unroll
    for (int dd = 0; dd < 16; dd++) {
        int d = dg*16 + dd;
        *(float4*)&ckvT[(tbase + d)*MP + mg*4] =
            make_float4(acc[0][dd], acc[1][dd], acc[2][dd], acc[3][dd]);
    }
    if (dg == 0) {
        #pragma unroll
        for (int mi=0;mi<4;mi++)
            cksum[(size_t)(bh*NCH + c)*MP + mg*4 + mi] = ks[mi];
    }
}

// exclusive prefix over chunks of ckvT -> split bf16 S^T (stride MPS, zero tail)
__global__ __launch_bounds__(256) void prefix_ckvT_kernel(
    const float* __restrict__ ckvT, ushort_t* __restrict__ cth, ushort_t* __restrict__ ctl)
{
    const int bh = blockIdx.y;
    const int dm = blockIdx.x * 256 + threadIdx.x;   // < 64*MPS
    if (dm >= 64*MPS) return;
    const int d = dm / MPS, m = dm % MPS;
    if (m < MP) {
        float run = 0.f;
        #pragma unroll
        for (int c = 0; c < NCH; c++) {
            size_t row = (size_t)(bh*NCH + c)*64 + d;
            ushort_t h, l;
            bsplit(run, h, l);
            cth[row*MPS + m] = h; ctl[row*MPS + m] = l;
            run += ckvT[row*MP + m];
        }
    } else {
        #pragma unroll
        for (int c = 0; c < NCH; c++) {
            size_t row = (size_t)(bh*NCH + c)*64 + d;
            cth[row*MPS + m] = 0; ctl[row*MPS + m] = 0;
        }
    }
}

__global__ __launch_bounds__(320) void prefix_ksum_kernel(float* __restrict__ cksum)
{
    const int bh = blockIdx.x;
    const int m = threadIdx.x;
    if (m >= MP) return;
    float run = 0.f;
    #pragma unroll
    for (int c = 0; c < NCH; c++) {
        size_t idx = (size_t)(bh*NCH + c)*MP + m;
        float v = cksum[idx];
        cksum[idx] = run;
        run += v;
    }
}

// q'_nm = q_nm / (excl-chunk-prefix + incl cumsum of k); in-place on split bf16
__global__ __launch_bounds__(320) void qprime_kernel(
    ushort_t* __restrict__ qph, ushort_t* __restrict__ qpl,
    const ushort_t* __restrict__ kph, const ushort_t* __restrict__ kpl,
    const float* __restrict__ cksum)
{
    const int c = blockIdx.x, bh = blockIdx.y;
    const int m = threadIdx.x;
    if (m >= MPS) return;
    size_t base = (size_t)(bh*NSEQ + c*CHK)*MPS + m;
    if (m < MF) {
        float run = cksum[(size_t)(bh*NCH + c)*MP + m];
        for (int i = 0; i < CHK; i++) {
            size_t idx = base + (size_t)i*MPS;
            run += b2f(kph[idx]) + b2f(kpl[idx]);
            float q = b2f(qph[idx]) + b2f(qpl[idx]);
            q /= run;
            ushort_t h, l;
            bsplit(q, h, l);
            qph[idx] = h; qpl[idx] = l;
        }
    } else {
        for (int i = 0; i < CHK; i++) {
            size_t idx = base + (size_t)i*MPS;
            qph[idx] = 0; qpl[idx] = 0;
        }
    }
}

// Per (b,h,chunk of 64): O = Q'@S^T + tril(Q'K^T)@V via split-bf16 MFMA.
// 4 waves (2x2), each 32x32 of P and O. Writes aout split bf16.
__global__ __launch_bounds__(256) void attn_mfma(
    const ushort_t* __restrict__ qph, const ushort_t* __restrict__ qpl,
    const ushort_t* __restrict__ kph, const ushort_t* __restrict__ kpl,
    const ushort_t* __restrict__ cth, const ushort_t* __restrict__ ctl,
    const float* __restrict__ qkv,
    ushort_t* __restrict__ aout_h, ushort_t* __restrict__ aout_l)
{
    __shared__ ushort_t tQh[64*LDT], tQl[64*LDT];
    __shared__ ushort_t tKh[64*LDT], tKl[64*LDT];
    __shared__ ushort_t tSh[64*LDT], tSl[64*LDT];
    __shared__ ushort_t VTh[64*LDP], VTl[64*LDP];
    __shared__ ushort_t Ph[64*LDP],  Pl[64*LDP];
    const int tid = threadIdx.x;
    const int c = blockIdx.x, bh = blockIdx.y, b = bh >> 3, hh = bh & 7;
    const size_t rowg = (size_t)bh*NSEQ + c*CHK;
    const size_t rowx = (size_t)b*NSEQ + c*CHK;
    const size_t sbase = (size_t)(bh*NCH + c)*64;

    // V chunk: transpose + split into VT[d][j]
    {
        const int j = tid >> 2, dq = (tid & 3) * 16;
        const float* vsrc = &qkv[(rowx + j)*(3*DIMX) + 2*DIMX + hh*DH + dq];
        #pragma unroll
        for (int p = 0; p < 4; p++) {
            float4 f = *(const float4*)&vsrc[p*4];
            float vr[4] = {f.x,f.y,f.z,f.w};
            #pragma unroll
            for (int wv = 0; wv < 4; wv++) {
                ushort_t h, l;
                bsplit(vr[wv], h, l);
                VTh[(dq + p*4 + wv)*LDP + j] = h;
                VTl[(dq + p*4 + wv)*LDP + j] = l;
            }
        }
    }

    const int lane = tid & 63, w = tid >> 6;
    const int wr = w >> 1, wc = w & 1;
    const int fr = lane & 15, fk = (lane >> 4) * 8;
    const int srow = tid >> 2, sseg = (tid & 3) * 8;   // staging: 64 rows x 4 segs
    f32x4 accP[2][2], accO[2][2];
    #pragma unroll
    for (int i=0;i<2;i++)
        #pragma unroll
        for (int j=0;j<2;j++){ accP[i][j]=(f32x4){0,0,0,0}; accO[i][j]=(f32x4){0,0,0,0}; }

    for (int m0 = 0; m0 < MPS; m0 += 32) {
        uint4 gq_h = *(const uint4*)&qph[(rowg + srow)*MPS + m0 + sseg];
        uint4 gq_l = *(const uint4*)&qpl[(rowg + srow)*MPS + m0 + sseg];
        uint4 gk_h = *(const uint4*)&kph[(rowg + srow)*MPS + m0 + sseg];
        uint4 gk_l = *(const uint4*)&kpl[(rowg + srow)*MPS + m0 + sseg];
        uint4 gs_h = *(const uint4*)&cth[(sbase + srow)*MPS + m0 + sseg];
        uint4 gs_l = *(const uint4*)&ctl[(sbase + srow)*MPS + m0 + sseg];
        __syncthreads();
        *(uint4*)&tQh[srow*LDT + sseg] = gq_h;
        *(uint4*)&tQl[srow*LDT + sseg] = gq_l;
        *(uint4*)&tKh[srow*LDT + sseg] = gk_h;
        *(uint4*)&tKl[srow*LDT + sseg] = gk_l;
        *(uint4*)&tSh[srow*LDT + sseg] = gs_h;
        *(uint4*)&tSl[srow*LDT + sseg] = gs_l;
        __syncthreads();
        short8 aQh[2], aQl[2], bKh[2], bKl[2], bSh[2], bSl[2];
        #pragma unroll
        for (int f = 0; f < 2; f++) {
            int ra = (wr*32 + f*16 + fr)*LDT + fk;
            int rb = (wc*32 + f*16 + fr)*LDT + fk;
            aQh[f] = *(const short8*)&tQh[ra];
            aQl[f] = *(const short8*)&tQl[ra];
            bKh[f] = *(const short8*)&tKh[rb];
            bKl[f] = *(const short8*)&tKl[rb];
            bSh[f] = *(const short8*)&tSh[rb];
            bSl[f] = *(const short8*)&tSl[rb];
        }
        #pragma unroll
        for (int i = 0; i < 2; i++)
            #pragma unroll
            for (int j = 0; j < 2; j++) {
                accP[i][j] = __builtin_amdgcn_mfma_f32_16x16x32_bf16(aQh[i], bKh[j], accP[i][j], 0, 0, 0);
                accP[i][j] = __builtin_amdgcn_mfma_f32_16x16x32_bf16(aQh[i], bKl[j], accP[i][j], 0, 0, 0);
                accP[i][j] = __builtin_amdgcn_mfma_f32_16x16x32_bf16(aQl[i], bKh[j], accP[i][j], 0, 0, 0);
                accO[i][j] = __builtin_amdgcn_mfma_f32_16x16x32_bf16(aQh[i], bSh[j], accO[i][j], 0, 0, 0);
                accO[i][j] = __builtin_amdgcn_mfma_f32_16x16x32_bf16(aQh[i], bSl[j], accO[i][j], 0, 0, 0);
                accO[i][j] = __builtin_amdgcn_mfma_f32_16x16x32_bf16(aQl[i], bSh[j], accO[i][j], 0, 0, 0);
            }
    }

    // tril mask + split P into LDS
    __syncthreads();
    {
        const int crow = (lane >> 4) * 4, ccol = lane & 15;
        #pragma unroll
        for (int i = 0; i < 2; i++)
            #pragma unroll
            for (int j = 0; j < 2; j++) {
                int colg = wc*32 + j*16 + ccol;
                #pragma unroll
                for (int rr = 0; rr < 4; rr++) {
                    int rowg2 = wr*32 + i*16 + crow + rr;
                    float v = (colg <= rowg2) ? accP[i][j][rr] : 0.f;
                    ushort_t h, l;
                    bsplit(v, h, l);
                    Ph[rowg2*LDP + colg] = h;
                    Pl[rowg2*LDP + colg] = l;
                }
            }
    }
    __syncthreads();

    // O += P @ V   (B^T form via VT[d][j])
    #pragma unroll
    for (int js = 0; js < 2; js++) {
        short8 aPh[2], aPl[2], bVh[2], bVl[2];
        #pragma unroll
        for (int f = 0; f < 2; f++) {
            int ra = (wr*32 + f*16 + fr)*LDP + js*32 + fk;
            int rb = (wc*32 + f*16 + fr)*LDP + js*32 + fk;
            aPh[f] = *(const short8*)&Ph[ra];
            aPl[f] = *(const short8*)&Pl[ra];
            bVh[f] = *(const short8*)&VTh[rb];
            bVl[f] = *(const short8*)&VTl[rb];
        }
        #pragma unroll
        for (int i = 0; i < 2; i++)
            #pragma unroll
            for (int j = 0; j < 2; j++) {
                accO[i][j] = __builtin_amdgcn_mfma_f32_16x16x32_bf16(aPh[i], bVh[j], accO[i][j], 0, 0, 0);
                accO[i][j] = __builtin_amdgcn_mfma_f32_16x16x32_bf16(aPh[i], bVl[j], accO[i][j], 0, 0, 0);
                accO[i][j] = __builtin_amdgcn_mfma_f32_16x16x32_bf16(aPl[i], bVh[j], accO[i][j], 0, 0, 0);
            }
    }

    // epilogue: split accO -> aout hi/lo
    {
        const int crow = (lane >> 4) * 4, ccol = lane & 15;
        #pragma unroll
        for (int i = 0; i < 2; i++)
            #pragma unroll
            for (int j = 0; j < 2; j++) {
                int d = wc*32 + j*16 + ccol;
                #pragma unroll
                for (int rr = 0; rr < 4; rr++) {
                    int row = wr*32 + i*16 + crow + rr;
                    size_t o = (rowx + row)*DIMX + hh*DH + d;
                    ushort_t h, l;
                    bsplit(accO[i][j][rr], h, l);
                    aout_h[o] = h; aout_l[o] = l;
                }
            }
    }
}

extern "C" void kernel_launch(void* const* d_in, const int* in_sizes, int n_in,
                              void* d_out, int out_size, void* d_ws, size_t ws_size,
                              hipStream_t stream)
{
    (void)in_sizes; (void)n_in; (void)out_size; (void)ws_size;
    const float* x     = (const float*)d_in[0];
    const float* w_qkv = (const float*)d_in[1];
    const float* w_out = (const float*)d_in[2];
    const float* b_out = (const float*)d_in[3];
    const float* proj  = (const float*)d_in[4];
    float* out = (float*)d_out;

    char* ws = (char*)d_ws;
    size_t off = 0;
    auto alloc = [&](size_t bytes) -> char* {
        char* p = ws + off;
        off += (bytes + 255) & ~(size_t)255;
        return p;
    };
    float* qkv       = (float*)alloc((size_t)NROWS*3*DIMX*sizeof(float));        // 25.2 MB
    float* dash      = (float*)alloc((size_t)NBH*NSEQ*MP*sizeof(float));         // 35.7 MB (raw K dash; later aliased as ckvT)
    ushort_t* qph    = (ushort_t*)alloc((size_t)NBH*NSEQ*MPS*sizeof(ushort_t));  // 18.9 MB
    ushort_t* qpl    = (ushort_t*)alloc((size_t)NBH*NSEQ*MPS*sizeof(ushort_t));
    ushort_t* kph    = (ushort_t*)alloc((size_t)NBH*NSEQ*MPS*sizeof(ushort_t));
    ushort_t* kpl    = (ushort_t*)alloc((size_t)NBH*NSEQ*MPS*sizeof(ushort_t));
    ushort_t* cth    = (ushort_t*)alloc((size_t)NBH*NCH*64*MPS*sizeof(ushort_t)); // 18.9 MB
    ushort_t* ctl    = (ushort_t*)alloc((size_t)NBH*NCH*64*MPS*sizeof(ushort_t));
    float* cksum     = (float*)alloc((size_t)NBH*NCH*MP*sizeof(float));
    float* diagk     = (float*)alloc((size_t)NBH*NSEQ*sizeof(float));
    unsigned* gmax   = (unsigned*)alloc(256);
    ushort_t* xs_h   = (ushort_t*)alloc((size_t)NROWS*DIMX*sizeof(ushort_t));    // aliased: aout_h
    ushort_t* xs_l   = (ushort_t*)alloc((size_t)NROWS*DIMX*sizeof(ushort_t));    // aliased: aout_l
    ushort_t* wqt_h  = (ushort_t*)alloc((size_t)(3*DIMX)*DIMX*sizeof(ushort_t));
    ushort_t* wqt_l  = (ushort_t*)alloc((size_t)(3*DIMX)*DIMX*sizeof(ushort_t));
    ushort_t* wot_h  = (ushort_t*)alloc((size_t)DIMX*DIMX*sizeof(ushort_t));
    ushort_t* wot_l  = (ushort_t*)alloc((size_t)DIMX*DIMX*sizeof(ushort_t));
    float* ckvT      = dash;     // alias: dash is dead after kexp, same 35.65 MB footprint
    ushort_t* aout_h = xs_h;
    ushort_t* aout_l = xs_l;

    const float nrm   = (float)pow(64.0, -0.25);   // 2^-1.5
    const float ratio = (float)(1.0 / sqrt(266.0));

    hipMemsetAsync(gmax, 0, sizeof(unsigned), stream);
    // input splits
    split_kernel<<<dim3((NROWS*DIMX/4 + 255)/256), 256, 0, stream>>>(x, xs_h, xs_l, NROWS*DIMX/4);
    splitT_kernel<<<dim3(3*DIMX/64, DIMX/64), 256, 0, stream>>>(w_qkv, wqt_h, wqt_l, DIMX, 3*DIMX);
    splitT_kernel<<<dim3(DIMX/64, DIMX/64), 256, 0, stream>>>(w_out, wot_h, wot_l, DIMX, DIMX);
    // qkv = x @ w_qkv  (split-bf16 MFMA)
    gemm_bf16s<<<dim3(3*DIMX/128, NROWS/128), 256, 0, stream>>>(
        xs_h, xs_l, wqt_h, wqt_l, nullptr, qkv, NROWS, 3*DIMX, DIMX);
    // feature maps
    feat_kernel<true ><<<dim3(32, 16), 256, 0, stream>>>(
        qkv, proj, nullptr, qph, qpl, nullptr, nullptr, 0, nrm, ratio);
    feat_kernel<false><<<dim3(32, 16), 256, 0, stream>>>(
        qkv, proj, dash, nullptr, nullptr, diagk, gmax, DIMX, nrm, ratio);
    kexp_kernel<<<dim3((NBH*NSEQ*(MPS/4) + 255)/256), 256, 0, stream>>>(
        dash, diagk, gmax, kph, kpl, ratio);
    // chunk scan (C=64)  — note: ckvT aliases dash (dash dead after kexp)
    chunk_sums_kernel<<<dim3(NCH, NBH), 320, 0, stream>>>(kph, kpl, qkv, ckvT, cksum);
    prefix_ckvT_kernel<<<dim3((64*MPS + 255)/256, NBH), 256, 0, stream>>>(ckvT, cth, ctl);
    prefix_ksum_kernel<<<dim3(NBH), 320, 0, stream>>>(cksum);
    qprime_kernel<<<dim3(NCH, NBH), 320, 0, stream>>>(qph, qpl, kph, kpl, cksum);
    attn_mfma<<<dim3(NCH, NBH), 256, 0, stream>>>(
        qph, qpl, kph, kpl, cth, ctl, qkv, aout_h, aout_l);
    // out = aout @ w_out + b_out  (split-bf16 MFMA)
    gemm_bf16s<<<dim3(DIMX/128, NROWS/128), 256, 0, stream>>>(
        aout_h, aout_l, wot_h, wot_l, b_out, out, NROWS, DIMX, DIMX);
}

// Round 8
// 248.637 us; speedup vs baseline: 1.7585x; 1.0810x over previous
//
#include <hip/hip_runtime.h>
#include <math.h>

#define DIMX 512
#define NHEADS 8
#define DH 64
#define MF 266            // real feature count
#define MP 272            // padded feature count (16-multiple)
#define MPS 288           // padded stride for split bf16 arrays (32-multiple)
#define NB 2
#define NSEQ 2048
#define NROWS (NB*NSEQ)   // 4096
#define NBH 16
#define CHK 64
#define NCH 32
#define EPSF 1e-4f
#define LDT 40            // LDS row stride (ushort) for gemm tiles
#define LDP 72            // LDS row stride (ushort) for P/VT/feat tiles

typedef __attribute__((ext_vector_type(8))) short short8;
typedef __attribute__((ext_vector_type(4))) float f32x4;
typedef unsigned short ushort_t;

__device__ __forceinline__ unsigned fkey(float f){
    unsigned u = __float_as_uint(f);
    return (f < 0.0f) ? ~u : (u | 0x80000000u);
}
__device__ __forceinline__ float fdec(unsigned k){
    unsigned u = (k & 0x80000000u) ? (k & 0x7fffffffu) : ~k;
    return __uint_as_float(u);
}
__device__ __forceinline__ float b2f(ushort_t u){
    return __uint_as_float(((unsigned)u) << 16);
}

// split fp32 a into bf16 hi + bf16 lo (RNE both): a ≈ hi + lo, residual ~2^-17|a|
__device__ __forceinline__ void bsplit(float a, ushort_t& h, ushort_t& l){
    unsigned u = __float_as_uint(a);
    unsigned r = (u + 0x7fffu + ((u >> 16) & 1u)) & 0xffff0000u;
    h = (ushort_t)(r >> 16);
    float res = a - __uint_as_float(r);
    unsigned v = __float_as_uint(res);
    unsigned r2 = v + 0x7fffu + ((v >> 16) & 1u);
    l = (ushort_t)(r2 >> 16);
}

// elementwise split: A fp32 [total4*4] -> H,L bf16
__global__ __launch_bounds__(256) void split_kernel(
    const float* __restrict__ A, ushort_t* __restrict__ H, ushort_t* __restrict__ L, int total4)
{
    int i = blockIdx.x * 256 + threadIdx.x;
    if (i >= total4) return;
    float4 f = ((const float4*)A)[i];
    ushort_t h0,h1,h2,h3,l0,l1,l2,l3;
    bsplit(f.x,h0,l0); bsplit(f.y,h1,l1); bsplit(f.z,h2,l2); bsplit(f.w,h3,l3);
    ((ushort4*)H)[i] = make_ushort4(h0,h1,h2,h3);
    ((ushort4*)L)[i] = make_ushort4(l0,l1,l2,l3);
}

// W [K][N] fp32 -> Th,Tl [N][K] bf16 (transpose + split), 64x64 tiles
__global__ __launch_bounds__(256) void splitT_kernel(
    const float* __restrict__ W, ushort_t* __restrict__ Th, ushort_t* __restrict__ Tl,
    int K, int N)
{
    __shared__ ushort_t Sh[64][72], Sl[64][72];
    const int k0 = blockIdx.y * 64, n0 = blockIdx.x * 64;
    const int tid = threadIdx.x;
    {
        const int kk = tid >> 4, nq = (tid & 15) * 4;
        for (int p = 0; p < 4; p++) {
            int k = p*16 + kk;
            float4 f = *(const float4*)&W[(size_t)(k0 + k)*N + n0 + nq];
            ushort_t h, l;
            bsplit(f.x,h,l); Sh[nq+0][k]=h; Sl[nq+0][k]=l;
            bsplit(f.y,h,l); Sh[nq+1][k]=h; Sl[nq+1][k]=l;
            bsplit(f.z,h,l); Sh[nq+2][k]=h; Sl[nq+2][k]=l;
            bsplit(f.w,h,l); Sh[nq+3][k]=h; Sl[nq+3][k]=l;
        }
    }
    __syncthreads();
    {
        const int n = tid >> 2, ks = (tid & 3) * 16;
        for (int q = 0; q < 2; q++) {
            uint4 vh = *(const uint4*)&Sh[n][ks + q*8];
            uint4 vl = *(const uint4*)&Sl[n][ks + q*8];
            *(uint4*)&Th[(size_t)(n0 + n)*K + k0 + ks + q*8] = vh;
            *(uint4*)&Tl[(size_t)(n0 + n)*K + k0 + ks + q*8] = vl;
        }
    }
}

// proj [MF][64] fp32 -> pjh/pjl [MPS][64] bf16 of nrm*proj (zero-pad m>=MF)
__global__ __launch_bounds__(256) void splitP_kernel(
    const float* __restrict__ proj, ushort_t* __restrict__ ph, ushort_t* __restrict__ pl,
    float nrm)
{
    int idx = blockIdx.x * 256 + threadIdx.x;    // over MPS*64/4
    if (idx >= MPS*64/4) return;
    int m = idx >> 4, kq = (idx & 15) * 4;
    ushort4 h4 = make_ushort4(0,0,0,0), l4 = make_ushort4(0,0,0,0);
    if (m < MF) {
        float4 f = *(const float4*)&proj[m*64 + kq];
        ushort_t hh[4], ll[4];
        bsplit(f.x*nrm,hh[0],ll[0]); bsplit(f.y*nrm,hh[1],ll[1]);
        bsplit(f.z*nrm,hh[2],ll[2]); bsplit(f.w*nrm,hh[3],ll[3]);
        h4 = make_ushort4(hh[0],hh[1],hh[2],hh[3]);
        l4 = make_ushort4(ll[0],ll[1],ll[2],ll[3]);
    }
    *(ushort4*)&ph[(size_t)m*64 + kq] = h4;
    *(ushort4*)&pl[(size_t)m*64 + kq] = l4;
}

// C[M][N] = (Ah+Al)[M][K] @ (Bh+Bl)^T[N][K] (+bias) via 3x bf16 MFMA split.
__global__ __launch_bounds__(256) void gemm_bf16s(
    const ushort_t* __restrict__ Ah, const ushort_t* __restrict__ Al,
    const ushort_t* __restrict__ Bh, const ushort_t* __restrict__ Bl,
    const float* __restrict__ bias, float* __restrict__ C,
    int M, int N, int K)
{
    __shared__ ushort_t sAh[128*LDT], sAl[128*LDT], sBh[128*LDT], sBl[128*LDT];
    const int tid = threadIdx.x;
    const int m0 = blockIdx.y * 128, n0 = blockIdx.x * 128;
    const int lane = tid & 63, w = tid >> 6;
    const int wr = w >> 1, wc = w & 1;
    const int lr = lane & 15;
    const int lsu = (lane >> 4) * 8;
    const int r = tid >> 1, sg = (tid & 1) * 16;
    const size_t gA = (size_t)(m0 + r)*K + sg;
    const size_t gB = (size_t)(n0 + r)*K + sg;

    f32x4 acc[4][4];
    #pragma unroll
    for (int i=0;i<4;i++)
        #pragma unroll
        for (int j=0;j<4;j++) acc[i][j] = (f32x4){0.f,0.f,0.f,0.f};

    for (int k0 = 0; k0 < K; k0 += 32) {
        uint4 a0 = *(const uint4*)&Ah[gA + k0];
        uint4 a1 = *(const uint4*)&Ah[gA + k0 + 8];
        uint4 a2 = *(const uint4*)&Al[gA + k0];
        uint4 a3 = *(const uint4*)&Al[gA + k0 + 8];
        uint4 b0 = *(const uint4*)&Bh[gB + k0];
        uint4 b1 = *(const uint4*)&Bh[gB + k0 + 8];
        uint4 b2 = *(const uint4*)&Bl[gB + k0];
        uint4 b3 = *(const uint4*)&Bl[gB + k0 + 8];
        __syncthreads();
        *(uint4*)&sAh[r*LDT + sg]     = a0;
        *(uint4*)&sAh[r*LDT + sg + 8] = a1;
        *(uint4*)&sAl[r*LDT + sg]     = a2;
        *(uint4*)&sAl[r*LDT + sg + 8] = a3;
        *(uint4*)&sBh[r*LDT + sg]     = b0;
        *(uint4*)&sBh[r*LDT + sg + 8] = b1;
        *(uint4*)&sBl[r*LDT + sg]     = b2;
        *(uint4*)&sBl[r*LDT + sg + 8] = b3;
        __syncthreads();
        short8 afh[4], afl[4], bfh[4], bfl[4];
        #pragma unroll
        for (int f = 0; f < 4; f++) {
            int ra = (wr*64 + f*16 + lr)*LDT + lsu;
            int rb = (wc*64 + f*16 + lr)*LDT + lsu;
            afh[f] = *(const short8*)&sAh[ra];
            afl[f] = *(const short8*)&sAl[ra];
            bfh[f] = *(const short8*)&sBh[rb];
            bfl[f] = *(const short8*)&sBl[rb];
        }
        #pragma unroll
        for (int i = 0; i < 4; i++)
            #pragma unroll
            for (int j = 0; j < 4; j++) {
                acc[i][j] = __builtin_amdgcn_mfma_f32_16x16x32_bf16(afh[i], bfh[j], acc[i][j], 0, 0, 0);
                acc[i][j] = __builtin_amdgcn_mfma_f32_16x16x32_bf16(afh[i], bfl[j], acc[i][j], 0, 0, 0);
                acc[i][j] = __builtin_amdgcn_mfma_f32_16x16x32_bf16(afl[i], bfh[j], acc[i][j], 0, 0, 0);
            }
    }
    const int crow = (lane >> 4) * 4, ccol = lane & 15;
    #pragma unroll
    for (int i = 0; i < 4; i++) {
        #pragma unroll
        for (int j = 0; j < 4; j++) {
            int col = n0 + wc*64 + j*16 + ccol;
            float bb = bias ? bias[col] : 0.f;
            #pragma unroll
            for (int rr = 0; rr < 4; rr++) {
                int row = m0 + wr*64 + i*16 + crow + rr;
                C[(size_t)row*N + col] = acc[i][j][rr] + bb;
            }
        }
    }
}

// Feature map via split-bf16 MFMA: dash = data @ (nrm*proj)^T for 64 rows of one (b,h).
// IS_Q: qp = ratio*(exp(dash - diag - rowmax)+eps) -> oh/ol split.
// !IS_Q: raw dash -> oh/ol split (kph/kpl), diag_out, global atomicMax.
template<bool IS_Q>
__global__ __launch_bounds__(256) void feat_mfma(
    const float* __restrict__ qkv,
    const ushort_t* __restrict__ pjh, const ushort_t* __restrict__ pjl,
    ushort_t* __restrict__ oh, ushort_t* __restrict__ ol,
    float* __restrict__ diag_out, unsigned* __restrict__ gmax,
    int coff, float ratio)
{
    __shared__ ushort_t sDh[64*LDP], sDl[64*LDP];
    __shared__ ushort_t sPh[32*LDP], sPl[32*LDP];
    __shared__ float dsqs[64];
    const int tid = threadIdx.x;
    const int bh = blockIdx.y, b = bh >> 3, h = bh & 7;
    const int n0 = blockIdx.x * 64;
    // load data, per-row sum of squares, split to LDS
    {
        const int r = tid >> 2, sgq = (tid & 3) * 16;
        const float* src = &qkv[(size_t)(b*NSEQ + n0 + r)*(3*DIMX) + coff + h*DH + sgq];
        float vals[16];
        float ss = 0.f;
        #pragma unroll
        for (int p = 0; p < 4; p++) {
            float4 f = *(const float4*)&src[p*4];
            vals[p*4+0]=f.x; vals[p*4+1]=f.y; vals[p*4+2]=f.z; vals[p*4+3]=f.w;
            ss = fmaf(f.x,f.x, fmaf(f.y,f.y, fmaf(f.z,f.z, fmaf(f.w,f.w, ss))));
        }
        ss += __shfl_xor(ss, 1, 64);
        ss += __shfl_xor(ss, 2, 64);
        if ((tid & 3) == 0) dsqs[r] = ss;
        #pragma unroll
        for (int p = 0; p < 16; p++) {
            ushort_t hh2, ll2;
            bsplit(vals[p], hh2, ll2);
            sDh[r*LDP + sgq + p] = hh2;
            sDl[r*LDP + sgq + p] = ll2;
        }
    }
    __syncthreads();
    const int lane = tid & 63, w = tid >> 6;
    const int fr = lane & 15, fk = (lane >> 4) * 8;
    // A-frags: wave w owns rows w*16..w*16+15, K=64 as 2 k-steps
    short8 aDh[2], aDl[2];
    #pragma unroll
    for (int ks = 0; ks < 2; ks++) {
        int ra = (w*16 + fr)*LDP + ks*32 + fk;
        aDh[ks] = *(const short8*)&sDh[ra];
        aDl[ks] = *(const short8*)&sDl[ra];
    }
    f32x4 acc[18];
    #pragma unroll
    for (int t = 0; t < 18; t++) acc[t] = (f32x4){0.f,0.f,0.f,0.f};
    #pragma unroll
    for (int it = 0; it < 9; it++) {
        const int m0 = it*32;
        __syncthreads();
        {
            int r2 = tid >> 3, sg2 = (tid & 7) * 8;
            *(uint4*)&sPh[r2*LDP + sg2] = *(const uint4*)&pjh[(size_t)(m0 + r2)*64 + sg2];
            *(uint4*)&sPl[r2*LDP + sg2] = *(const uint4*)&pjl[(size_t)(m0 + r2)*64 + sg2];
        }
        __syncthreads();
        #pragma unroll
        for (int mt = 0; mt < 2; mt++) {
            short8 bh_[2], bl_[2];
            #pragma unroll
            for (int ks = 0; ks < 2; ks++) {
                int rb = (mt*16 + fr)*LDP + ks*32 + fk;
                bh_[ks] = *(const short8*)&sPh[rb];
                bl_[ks] = *(const short8*)&sPl[rb];
            }
            #pragma unroll
            for (int ks = 0; ks < 2; ks++) {
                acc[it*2+mt] = __builtin_amdgcn_mfma_f32_16x16x32_bf16(aDh[ks], bh_[ks], acc[it*2+mt], 0, 0, 0);
                acc[it*2+mt] = __builtin_amdgcn_mfma_f32_16x16x32_bf16(aDh[ks], bl_[ks], acc[it*2+mt], 0, 0, 0);
                acc[it*2+mt] = __builtin_amdgcn_mfma_f32_16x16x32_bf16(aDl[ks], bh_[ks], acc[it*2+mt], 0, 0, 0);
            }
        }
    }
    // epilogue
    const size_t rbase = (size_t)bh*NSEQ + n0;
    const int crow = (lane >> 4) * 4, ccol = lane & 15;
    const int rw = w*16 + crow;
    float dg0[4];
    #pragma unroll
    for (int rr = 0; rr < 4; rr++) dg0[rr] = 0.0625f * dsqs[rw + rr];

    if (IS_Q) {
        #pragma unroll
        for (int rr = 0; rr < 4; rr++) {
            float mx = -1e30f;
            #pragma unroll
            for (int t = 0; t < 18; t++) {
                bool valid = (t < 16) || (t == 16 && ccol < (MF - 256));
                if (valid) mx = fmaxf(mx, acc[t][rr]);
            }
            mx = fmaxf(mx, __shfl_xor(mx, 1, 64));
            mx = fmaxf(mx, __shfl_xor(mx, 2, 64));
            mx = fmaxf(mx, __shfl_xor(mx, 4, 64));
            mx = fmaxf(mx, __shfl_xor(mx, 8, 64));
            float sub = dg0[rr] + mx;
            ushort_t* orh = &oh[(rbase + rw + rr)*MPS + ccol];
            ushort_t* orl = &ol[(rbase + rw + rr)*MPS + ccol];
            #pragma unroll
            for (int t = 0; t < 18; t++) {
                bool valid = (t < 16) || (t == 16 && ccol < (MF - 256));
                float v = valid ? ratio*(expf(acc[t][rr] - sub) + EPSF) : 0.f;
                ushort_t hh2, ll2; bsplit(v, hh2, ll2);
                orh[t*16] = hh2; orl[t*16] = ll2;
            }
        }
    } else {
        float wmax = -1e30f;
        #pragma unroll
        for (int rr = 0; rr < 4; rr++) {
            if (ccol == 0) diag_out[rbase + rw + rr] = dg0[rr];
            ushort_t* orh = &oh[(rbase + rw + rr)*MPS + ccol];
            ushort_t* orl = &ol[(rbase + rw + rr)*MPS + ccol];
            #pragma unroll
            for (int t = 0; t < 18; t++) {
                float v = acc[t][rr];
                bool valid = (t < 16) || (t == 16 && ccol < (MF - 256));
                if (valid) wmax = fmaxf(wmax, v);
                ushort_t hh2, ll2; bsplit(v, hh2, ll2);
                orh[t*16] = hh2; orl[t*16] = ll2;
            }
        }
        #pragma unroll
        for (int o = 1; o < 64; o <<= 1) wmax = fmaxf(wmax, __shfl_xor(wmax, o, 64));
        if (lane == 0) atomicMax(gmax, fkey(wmax));
    }
}

// in-place: k = ratio*(exp(dash - diag - stab) + eps) on split bf16 (zero tail)
__global__ __launch_bounds__(256) void kexp_kernel(
    ushort_t* __restrict__ kph, ushort_t* __restrict__ kpl,
    const float* __restrict__ diagk, const unsigned* __restrict__ gmax, float ratio)
{
    unsigned gid = blockIdx.x * 256u + threadIdx.x;
    if (gid >= (unsigned)(NBH*NSEQ*(MPS/4))) return;
    unsigned row = gid / (MPS/4);
    int mq = (int)(gid % (MPS/4)) * 4;
    const float stab = fdec(*gmax);
    const float dg = diagk[row];
    size_t idx = (size_t)row*MPS + mq;
    ushort4 h4 = *(const ushort4*)&kph[idx];
    ushort4 l4 = *(const ushort4*)&kpl[idx];
    float dv[4] = {b2f(h4.x)+b2f(l4.x), b2f(h4.y)+b2f(l4.y),
                   b2f(h4.z)+b2f(l4.z), b2f(h4.w)+b2f(l4.w)};
    ushort_t hh[4], ll[4];
    #pragma unroll
    for (int j = 0; j < 4; j++) {
        float kv = (mq + j < MF) ? ratio * (expf(dv[j] - dg - stab) + EPSF) : 0.f;
        bsplit(kv, hh[j], ll[j]);
    }
    *(ushort4*)&kph[idx] = make_ushort4(hh[0],hh[1],hh[2],hh[3]);
    *(ushort4*)&kpl[idx] = make_ushort4(ll[0],ll[1],ll[2],ll[3]);
}

// Per (b,h,chunk): ckvT[d][m] = (K_c^T V_c)^T, cksum[m] = col-sums of K_c
__global__ __launch_bounds__(320) void chunk_sums_kernel(
    const ushort_t* __restrict__ kph, const ushort_t* __restrict__ kpl,
    const float* __restrict__ qkv,
    float* __restrict__ ckvT, float* __restrict__ cksum)
{
    __shared__ float vs[CHK][DH];
    const int tid = threadIdx.x;
    const int c = blockIdx.x, bh = blockIdx.y, b = bh >> 3, h = bh & 7;
    for (int idx = tid; idx < CHK*16; idx += 320) {
        int i = idx >> 4, q = idx & 15;
        *(float4*)&vs[i][q*4] =
            *(const float4*)&qkv[(size_t)(b*NSEQ + c*CHK + i)*(3*DIMX) + 2*DIMX + h*DH + q*4];
    }
    __syncthreads();
    if (tid >= 272) return;
    const int mg = tid % 68, dg = tid / 68;   // m block of 4, d block of 16
    float acc[4][16] = {};
    float ks[4] = {0.f,0.f,0.f,0.f};
    const size_t kbase = (size_t)(bh*NSEQ + c*CHK)*MPS + mg*4;
    for (int i = 0; i < CHK; i++) {
        ushort4 kh = *(const ushort4*)&kph[kbase + (size_t)i*MPS];
        ushort4 kl = *(const ushort4*)&kpl[kbase + (size_t)i*MPS];
        float kr[4] = {b2f(kh.x)+b2f(kl.x), b2f(kh.y)+b2f(kl.y),
                       b2f(kh.z)+b2f(kl.z), b2f(kh.w)+b2f(kl.w)};
        if (dg == 0) { ks[0]+=kr[0]; ks[1]+=kr[1]; ks[2]+=kr[2]; ks[3]+=kr[3]; }
        #pragma unroll
        for (int t = 0; t < 4; t++) {
            float4 vv = *(const float4*)&vs[i][dg*16 + t*4];
            float vr[4] = {vv.x,vv.y,vv.z,vv.w};
            #pragma unroll
            for (int mi=0;mi<4;mi++){
                acc[mi][t*4+0] = fmaf(kr[mi], vr[0], acc[mi][t*4+0]);
                acc[mi][t*4+1] = fmaf(kr[mi], vr[1], acc[mi][t*4+1]);
                acc[mi][t*4+2] = fmaf(kr[mi], vr[2], acc[mi][t*4+2]);
                acc[mi][t*4+3] = fmaf(kr[mi], vr[3], acc[mi][t*4+3]);
            }
        }
    }
    const size_t tbase = (size_t)(bh*NCH + c)*64;
    #pragma unroll
    for (int dd = 0; dd < 16; dd++) {
        int d = dg*16 + dd;
        *(float4*)&ckvT[(tbase + d)*MP + mg*4] =
            make_float4(acc[0][dd], acc[1][dd], acc[2][dd], acc[3][dd]);
    }
    if (dg == 0) {
        #pragma unroll
        for (int mi=0;mi<4;mi++)
            cksum[(size_t)(bh*NCH + c)*MP + mg*4 + mi] = ks[mi];
    }
}

// exclusive prefix over chunks of ckvT -> split bf16 S^T (stride MPS, zero tail)
__global__ __launch_bounds__(256) void prefix_ckvT_kernel(
    const float* __restrict__ ckvT, ushort_t* __restrict__ cth, ushort_t* __restrict__ ctl)
{
    const int bh = blockIdx.y;
    const int dm = blockIdx.x * 256 + threadIdx.x;   // < 64*MPS
    if (dm >= 64*MPS) return;
    const int d = dm / MPS, m = dm % MPS;
    if (m < MP) {
        float run = 0.f;
        #pragma unroll
        for (int c = 0; c < NCH; c++) {
            size_t row = (size_t)(bh*NCH + c)*64 + d;
            ushort_t h, l;
            bsplit(run, h, l);
            cth[row*MPS + m] = h; ctl[row*MPS + m] = l;
            run += ckvT[row*MP + m];
        }
    } else {
        #pragma unroll
        for (int c = 0; c < NCH; c++) {
            size_t row = (size_t)(bh*NCH + c)*64 + d;
            cth[row*MPS + m] = 0; ctl[row*MPS + m] = 0;
        }
    }
}

__global__ __launch_bounds__(320) void prefix_ksum_kernel(float* __restrict__ cksum)
{
    const int bh = blockIdx.x;
    const int m = threadIdx.x;
    if (m >= MP) return;
    float run = 0.f;
    #pragma unroll
    for (int c = 0; c < NCH; c++) {
        size_t idx = (size_t)(bh*NCH + c)*MP + m;
        float v = cksum[idx];
        cksum[idx] = run;
        run += v;
    }
}

// q'_nm = q_nm / (excl-chunk-prefix + incl cumsum of k); in-place on split bf16
__global__ __launch_bounds__(320) void qprime_kernel(
    ushort_t* __restrict__ qph, ushort_t* __restrict__ qpl,
    const ushort_t* __restrict__ kph, const ushort_t* __restrict__ kpl,
    const float* __restrict__ cksum)
{
    const int c = blockIdx.x, bh = blockIdx.y;
    const int m = threadIdx.x;
    if (m >= MPS) return;
    size_t base = (size_t)(bh*NSEQ + c*CHK)*MPS + m;
    if (m < MF) {
        float run = cksum[(size_t)(bh*NCH + c)*MP + m];
        for (int i = 0; i < CHK; i++) {
            size_t idx = base + (size_t)i*MPS;
            run += b2f(kph[idx]) + b2f(kpl[idx]);
            float q = b2f(qph[idx]) + b2f(qpl[idx]);
            q /= run;
            ushort_t h, l;
            bsplit(q, h, l);
            qph[idx] = h; qpl[idx] = l;
        }
    } else {
        for (int i = 0; i < CHK; i++) {
            size_t idx = base + (size_t)i*MPS;
            qph[idx] = 0; qpl[idx] = 0;
        }
    }
}

// Per (b,h,chunk of 64): O = Q'@S^T + tril(Q'K^T)@V via split-bf16 MFMA.
__global__ __launch_bounds__(256) void attn_mfma(
    const ushort_t* __restrict__ qph, const ushort_t* __restrict__ qpl,
    const ushort_t* __restrict__ kph, const ushort_t* __restrict__ kpl,
    const ushort_t* __restrict__ cth, const ushort_t* __restrict__ ctl,
    const float* __restrict__ qkv,
    ushort_t* __restrict__ aout_h, ushort_t* __restrict__ aout_l)
{
    __shared__ ushort_t tQh[64*LDT], tQl[64*LDT];
    __shared__ ushort_t tKh[64*LDT], tKl[64*LDT];
    __shared__ ushort_t tSh[64*LDT], tSl[64*LDT];
    __shared__ ushort_t VTh[64*LDP], VTl[64*LDP];
    __shared__ ushort_t Ph[64*LDP],  Pl[64*LDP];
    const int tid = threadIdx.x;
    const int c = blockIdx.x, bh = blockIdx.y, b = bh >> 3, hh = bh & 7;
    const size_t rowg = (size_t)bh*NSEQ + c*CHK;
    const size_t rowx = (size_t)b*NSEQ + c*CHK;
    const size_t sbase = (size_t)(bh*NCH + c)*64;

    {
        const int j = tid >> 2, dq = (tid & 3) * 16;
        const float* vsrc = &qkv[(rowx + j)*(3*DIMX) + 2*DIMX + hh*DH + dq];
        #pragma unroll
        for (int p = 0; p < 4; p++) {
            float4 f = *(const float4*)&vsrc[p*4];
            float vr[4] = {f.x,f.y,f.z,f.w};
            #pragma unroll
            for (int wv = 0; wv < 4; wv++) {
                ushort_t h, l;
                bsplit(vr[wv], h, l);
                VTh[(dq + p*4 + wv)*LDP + j] = h;
                VTl[(dq + p*4 + wv)*LDP + j] = l;
            }
        }
    }

    const int lane = tid & 63, w = tid >> 6;
    const int wr = w >> 1, wc = w & 1;
    const int fr = lane & 15, fk = (lane >> 4) * 8;
    const int srow = tid >> 2, sseg = (tid & 3) * 8;
    f32x4 accP[2][2], accO[2][2];
    #pragma unroll
    for (int i=0;i<2;i++)
        #pragma unroll
        for (int j=0;j<2;j++){ accP[i][j]=(f32x4){0,0,0,0}; accO[i][j]=(f32x4){0,0,0,0}; }

    for (int m0 = 0; m0 < MPS; m0 += 32) {
        uint4 gq_h = *(const uint4*)&qph[(rowg + srow)*MPS + m0 + sseg];
        uint4 gq_l = *(const uint4*)&qpl[(rowg + srow)*MPS + m0 + sseg];
        uint4 gk_h = *(const uint4*)&kph[(rowg + srow)*MPS + m0 + sseg];
        uint4 gk_l = *(const uint4*)&kpl[(rowg + srow)*MPS + m0 + sseg];
        uint4 gs_h = *(const uint4*)&cth[(sbase + srow)*MPS + m0 + sseg];
        uint4 gs_l = *(const uint4*)&ctl[(sbase + srow)*MPS + m0 + sseg];
        __syncthreads();
        *(uint4*)&tQh[srow*LDT + sseg] = gq_h;
        *(uint4*)&tQl[srow*LDT + sseg] = gq_l;
        *(uint4*)&tKh[srow*LDT + sseg] = gk_h;
        *(uint4*)&tKl[srow*LDT + sseg] = gk_l;
        *(uint4*)&tSh[srow*LDT + sseg] = gs_h;
        *(uint4*)&tSl[srow*LDT + sseg] = gs_l;
        __syncthreads();
        short8 aQh[2], aQl[2], bKh[2], bKl[2], bSh[2], bSl[2];
        #pragma unroll
        for (int f = 0; f < 2; f++) {
            int ra = (wr*32 + f*16 + fr)*LDT + fk;
            int rb = (wc*32 + f*16 + fr)*LDT + fk;
            aQh[f] = *(const short8*)&tQh[ra];
            aQl[f] = *(const short8*)&tQl[ra];
            bKh[f] = *(const short8*)&tKh[rb];
            bKl[f] = *(const short8*)&tKl[rb];
            bSh[f] = *(const short8*)&tSh[rb];
            bSl[f] = *(const short8*)&tSl[rb];
        }
        #pragma unroll
        for (int i = 0; i < 2; i++)
            #pragma unroll
            for (int j = 0; j < 2; j++) {
                accP[i][j] = __builtin_amdgcn_mfma_f32_16x16x32_bf16(aQh[i], bKh[j], accP[i][j], 0, 0, 0);
                accP[i][j] = __builtin_amdgcn_mfma_f32_16x16x32_bf16(aQh[i], bKl[j], accP[i][j], 0, 0, 0);
                accP[i][j] = __builtin_amdgcn_mfma_f32_16x16x32_bf16(aQl[i], bKh[j], accP[i][j], 0, 0, 0);
                accO[i][j] = __builtin_amdgcn_mfma_f32_16x16x32_bf16(aQh[i], bSh[j], accO[i][j], 0, 0, 0);
                accO[i][j] = __builtin_amdgcn_mfma_f32_16x16x32_bf16(aQh[i], bSl[j], accO[i][j], 0, 0, 0);
                accO[i][j] = __builtin_amdgcn_mfma_f32_16x16x32_bf16(aQl[i], bSh[j], accO[i][j], 0, 0, 0);
            }
    }

    __syncthreads();
    {
        const int crow = (lane >> 4) * 4, ccol = lane & 15;
        #pragma unroll
        for (int i = 0; i < 2; i++)
            #pragma unroll
            for (int j = 0; j < 2; j++) {
                int colg = wc*32 + j*16 + ccol;
                #pragma unroll
                for (int rr = 0; rr < 4; rr++) {
                    int rowg2 = wr*32 + i*16 + crow + rr;
                    float v = (colg <= rowg2) ? accP[i][j][rr] : 0.f;
                    ushort_t h, l;
                    bsplit(v, h, l);
                    Ph[rowg2*LDP + colg] = h;
                    Pl[rowg2*LDP + colg] = l;
                }
            }
    }
    __syncthreads();

    #pragma unroll
    for (int js = 0; js < 2; js++) {
        short8 aPh[2], aPl[2], bVh[2], bVl[2];
        #pragma unroll
        for (int f = 0; f < 2; f++) {
            int ra = (wr*32 + f*16 + fr)*LDP + js*32 + fk;
            int rb = (wc*32 + f*16 + fr)*LDP + js*32 + fk;
            aPh[f] = *(const short8*)&Ph[ra];
            aPl[f] = *(const short8*)&Pl[ra];
            bVh[f] = *(const short8*)&VTh[rb];
            bVl[f] = *(const short8*)&VTl[rb];
        }
        #pragma unroll
        for (int i = 0; i < 2; i++)
            #pragma unroll
            for (int j = 0; j < 2; j++) {
                accO[i][j] = __builtin_amdgcn_mfma_f32_16x16x32_bf16(aPh[i], bVh[j], accO[i][j], 0, 0, 0);
                accO[i][j] = __builtin_amdgcn_mfma_f32_16x16x32_bf16(aPh[i], bVl[j], accO[i][j], 0, 0, 0);
                accO[i][j] = __builtin_amdgcn_mfma_f32_16x16x32_bf16(aPl[i], bVh[j], accO[i][j], 0, 0, 0);
            }
    }

    {
        const int crow = (lane >> 4) * 4, ccol = lane & 15;
        #pragma unroll
        for (int i = 0; i < 2; i++)
            #pragma unroll
            for (int j = 0; j < 2; j++) {
                int d = wc*32 + j*16 + ccol;
                #pragma unroll
                for (int rr = 0; rr < 4; rr++) {
                    int row = wr*32 + i*16 + crow + rr;
                    size_t o = (rowx + row)*DIMX + hh*DH + d;
                    ushort_t h, l;
                    bsplit(accO[i][j][rr], h, l);
                    aout_h[o] = h; aout_l[o] = l;
                }
            }
    }
}

extern "C" void kernel_launch(void* const* d_in, const int* in_sizes, int n_in,
                              void* d_out, int out_size, void* d_ws, size_t ws_size,
                              hipStream_t stream)
{
    (void)in_sizes; (void)n_in; (void)out_size; (void)ws_size;
    const float* x     = (const float*)d_in[0];
    const float* w_qkv = (const float*)d_in[1];
    const float* w_out = (const float*)d_in[2];
    const float* b_out = (const float*)d_in[3];
    const float* proj  = (const float*)d_in[4];
    float* out = (float*)d_out;

    char* ws = (char*)d_ws;
    size_t off = 0;
    auto alloc = [&](size_t bytes) -> char* {
        char* p = ws + off;
        off += (bytes + 255) & ~(size_t)255;
        return p;
    };
    float* qkv       = (float*)alloc((size_t)NROWS*3*DIMX*sizeof(float));        // 25.2 MB
    float* ckvT      = (float*)alloc((size_t)NBH*NCH*64*MP*sizeof(float));       // 35.7 MB
    ushort_t* qph    = (ushort_t*)alloc((size_t)NBH*NSEQ*MPS*sizeof(ushort_t));  // 18.9 MB
    ushort_t* qpl    = (ushort_t*)alloc((size_t)NBH*NSEQ*MPS*sizeof(ushort_t));
    ushort_t* kph    = (ushort_t*)alloc((size_t)NBH*NSEQ*MPS*sizeof(ushort_t));
    ushort_t* kpl    = (ushort_t*)alloc((size_t)NBH*NSEQ*MPS*sizeof(ushort_t));
    ushort_t* cth    = (ushort_t*)alloc((size_t)NBH*NCH*64*MPS*sizeof(ushort_t)); // 18.9 MB
    ushort_t* ctl    = (ushort_t*)alloc((size_t)NBH*NCH*64*MPS*sizeof(ushort_t));
    float* cksum     = (float*)alloc((size_t)NBH*NCH*MP*sizeof(float));
    float* diagk     = (float*)alloc((size_t)NBH*NSEQ*sizeof(float));
    unsigned* gmax   = (unsigned*)alloc(256);
    ushort_t* xs_h   = (ushort_t*)alloc((size_t)NROWS*DIMX*sizeof(ushort_t));    // aliased: aout_h
    ushort_t* xs_l   = (ushort_t*)alloc((size_t)NROWS*DIMX*sizeof(ushort_t));    // aliased: aout_l
    ushort_t* wqt_h  = (ushort_t*)alloc((size_t)(3*DIMX)*DIMX*sizeof(ushort_t));
    ushort_t* wqt_l  = (ushort_t*)alloc((size_t)(3*DIMX)*DIMX*sizeof(ushort_t));
    ushort_t* wot_h  = (ushort_t*)alloc((size_t)DIMX*DIMX*sizeof(ushort_t));
    ushort_t* wot_l  = (ushort_t*)alloc((size_t)DIMX*DIMX*sizeof(ushort_t));
    ushort_t* pjh    = (ushort_t*)alloc((size_t)MPS*64*sizeof(ushort_t));
    ushort_t* pjl    = (ushort_t*)alloc((size_t)MPS*64*sizeof(ushort_t));
    ushort_t* aout_h = xs_h;
    ushort_t* aout_l = xs_l;

    const float nrm   = (float)pow(64.0, -0.25);   // 2^-1.5
    const float ratio = (float)(1.0 / sqrt(266.0));

    hipMemsetAsync(gmax, 0, sizeof(unsigned), stream);
    // input splits
    split_kernel<<<dim3((NROWS*DIMX/4 + 255)/256), 256, 0, stream>>>(x, xs_h, xs_l, NROWS*DIMX/4);
    splitT_kernel<<<dim3(3*DIMX/64, DIMX/64), 256, 0, stream>>>(w_qkv, wqt_h, wqt_l, DIMX, 3*DIMX);
    splitT_kernel<<<dim3(DIMX/64, DIMX/64), 256, 0, stream>>>(w_out, wot_h, wot_l, DIMX, DIMX);
    splitP_kernel<<<dim3((MPS*64/4 + 255)/256), 256, 0, stream>>>(proj, pjh, pjl, nrm);
    // qkv = x @ w_qkv  (split-bf16 MFMA)
    gemm_bf16s<<<dim3(3*DIMX/128, NROWS/128), 256, 0, stream>>>(
        xs_h, xs_l, wqt_h, wqt_l, nullptr, qkv, NROWS, 3*DIMX, DIMX);
    // feature maps (split-bf16 MFMA)
    feat_mfma<true ><<<dim3(32, 16), 256, 0, stream>>>(
        qkv, pjh, pjl, qph, qpl, nullptr, nullptr, 0, ratio);
    feat_mfma<false><<<dim3(32, 16), 256, 0, stream>>>(
        qkv, pjh, pjl, kph, kpl, diagk, gmax, DIMX, ratio);
    kexp_kernel<<<dim3((NBH*NSEQ*(MPS/4) + 255)/256), 256, 0, stream>>>(
        kph, kpl, diagk, gmax, ratio);
    // chunk scan (C=64)
    chunk_sums_kernel<<<dim3(NCH, NBH), 320, 0, stream>>>(kph, kpl, qkv, ckvT, cksum);
    prefix_ckvT_kernel<<<dim3((64*MPS + 255)/256, NBH), 256, 0, stream>>>(ckvT, cth, ctl);
    prefix_ksum_kernel<<<dim3(NBH), 320, 0, stream>>>(cksum);
    qprime_kernel<<<dim3(NCH, NBH), 320, 0, stream>>>(qph, qpl, kph, kpl, cksum);
    attn_mfma<<<dim3(NCH, NBH), 256, 0, stream>>>(
        qph, qpl, kph, kpl, cth, ctl, qkv, aout_h, aout_l);
    // out = aout @ w_out + b_out  (split-bf16 MFMA)
    gemm_bf16s<<<dim3(DIMX/128, NROWS/128), 256, 0, stream>>>(
        aout_h, aout_l, wot_h, wot_l, b_out, out, NROWS, DIMX, DIMX);
}